// Round 4
// baseline (945.063 us; speedup 1.0000x reference)
//
#include <hip/hip_runtime.h>
#include <math.h>

#define BB 8
#define CC 512
#define HWN 16384
#define KK 150
#define KP 160
#define NSEG 16
#define SEGN (HWN / NSEG)  // 1024

typedef short bf8v __attribute__((ext_vector_type(8)));
typedef float f4v __attribute__((ext_vector_type(4)));

static __device__ inline unsigned short f2b(float f) {
  unsigned u = __float_as_uint(f);
  u += 0x7fffu + ((u >> 16) & 1u);
  return (unsigned short)(u >> 16);
}
static __device__ inline float b2f(unsigned short s) {
  return __uint_as_float(((unsigned)s) << 16);
}
static __device__ inline float b2fs(short s) { return b2f((unsigned short)s); }

typedef const __attribute__((address_space(1))) void* gas_p;
typedef __attribute__((address_space(3))) void* las_p;
// async 16B/lane global->LDS (LDS dest = wave base + lane*16, global src per-lane)
static __device__ __forceinline__ void gload16(const void* gp, void* lp) {
  __builtin_amdgcn_global_load_lds((gas_p)gp, (las_p)lp, 16, 0, 0);
}

// ---------------------------------------------------------------------------
// t0: cls16 [160][512] (rows>=150 zero), zero MT16, zero AC16 pad rows,
//     Wc16/Wf16 bf16 conversions.
// ---------------------------------------------------------------------------
__global__ __launch_bounds__(256) void t0_prep(const float* __restrict__ cls,
                                               const float* __restrict__ Wc,
                                               const float* __restrict__ Wf,
                                               unsigned short* __restrict__ cls16,
                                               unsigned short* __restrict__ Wc16,
                                               unsigned short* __restrict__ Wf16,
                                               unsigned short* __restrict__ MT16,
                                               unsigned short* __restrict__ AC16) {
  int i = blockIdx.x * 256 + threadIdx.x;
  if (i < KP * CC) {
    int k = i >> 9, c = i & 511;
    cls16[i] = (k < KK) ? f2b(cls[k * CC + c]) : 0;
  }
  if (i < BB * KP * KP) MT16[i] = 0;
  if (i < BB * (KP - KK) * CC) {
    int b = i / ((KP - KK) * CC);
    int r = i % ((KP - KK) * CC);
    int k = KK + (r >> 9);
    int c = r & 511;
    AC16[((size_t)b * KP + k) * CC + c] = 0;
  }
  if (i < CC * CC) {
    Wc16[i] = f2b(Wc[i]);
    Wf16[i] = f2b(Wf[i]);
  }
}

// ---------------------------------------------------------------------------
// t1: x [b][c][n] fp32 -> xT16 [b][n][c] bf16 (LDS transpose) + x16 [b][c][n]
// ---------------------------------------------------------------------------
__global__ __launch_bounds__(256) void t1_transpose(const float* __restrict__ x,
                                                    unsigned short* __restrict__ xT,
                                                    unsigned short* __restrict__ x16) {
  __shared__ float ts[32][65];
  const int n0 = blockIdx.x * 64, c0 = blockIdx.y * 32, b = blockIdx.z;
  const int tid = threadIdx.x;
  const float* xb = x + (size_t)b * CC * HWN;
  unsigned short* x16o = x16 + (size_t)b * CC * HWN;
#pragma unroll
  for (int i = 0; i < 2; i++) {
    int e = tid + i * 256;  // 0..511
    int c = e >> 4, n4 = (e & 15) * 4;
    float4 v = *(const float4*)&xb[(size_t)(c0 + c) * HWN + n0 + n4];
    ts[c][n4] = v.x;
    ts[c][n4 + 1] = v.y;
    ts[c][n4 + 2] = v.z;
    ts[c][n4 + 3] = v.w;
    ushort4 pk;
    pk.x = f2b(v.x);
    pk.y = f2b(v.y);
    pk.z = f2b(v.z);
    pk.w = f2b(v.w);
    *(ushort4*)&x16o[(size_t)(c0 + c) * HWN + n0 + n4] = pk;
  }
  __syncthreads();
  unsigned short* xo = xT + (size_t)b * HWN * CC;
#pragma unroll
  for (int i = 0; i < 2; i++) {
    int e = tid + i * 256;  // 0..511
    int cg = e & 7, n = e >> 3;
    ushort4 pk;
    pk.x = f2b(ts[4 * cg][n]);
    pk.y = f2b(ts[4 * cg + 1][n]);
    pk.z = f2b(ts[4 * cg + 2][n]);
    pk.w = f2b(ts[4 * cg + 3][n]);
    *(ushort4*)&xo[(size_t)(n0 + n) * CC + c0 + 4 * cg] = pk;
  }
}

// ---------------------------------------------------------------------------
// g1: A[k][n] = sum_c cls[k][c]*x[c][n] via MFMA with LDS-staged B (m97-style):
//   128-n block tile, BK=32, B staged via global_load_lds into 2x8KB buffers,
//   chunk-XOR swizzle on global source + ds_read slot (LDS linear).
// Epilogue (round-2, bit-identical math): E16, ET16, vvec.
// ---------------------------------------------------------------------------
__global__ __launch_bounds__(256) void g1_mfma(const unsigned short* __restrict__ xT,
                                               const unsigned short* __restrict__ cls16,
                                               unsigned short* __restrict__ E16,
                                               unsigned short* __restrict__ ET16,
                                               float* __restrict__ vvec) {
  __shared__ unsigned short sB[2][128 * 32];  // [n-row][32c], 64B rows
  const int n0 = blockIdx.x * 128, b = blockIdx.y;
  const int tid = threadIdx.x, w = tid >> 6, L = tid & 63;
  const int q = L >> 4, m16 = L & 15;
  f4v zf = {0.f, 0.f, 0.f, 0.f};
  f4v acc[10][2];
#pragma unroll
  for (int mt = 0; mt < 10; mt++) { acc[mt][0] = zf; acc[mt][1] = zf; }
  const unsigned short* cb = cls16 + (size_t)m16 * CC + 8 * q;
  // staging: wave w covers rows [w*32, w*32+32), 2 calls of 16 rows
  const int sr0 = w * 32 + (L >> 2);
  const int sch = L & 3;
  const unsigned short* xbase = xT + (size_t)(b * HWN + n0) * CC;

#define G1_STAGE(buf, c0)                                                      \
  {                                                                            \
    _Pragma("unroll") for (int j = 0; j < 2; j++) {                            \
      int row = sr0 + j * 16;                                                  \
      int ch = sch ^ ((row >> 1) & 3);                                         \
      gload16(xbase + (size_t)row * CC + (c0) + ch * 8,                        \
              &sB[buf][(w * 32 + j * 16) * 32]);                               \
    }                                                                          \
  }

  G1_STAGE(0, 0);
  __syncthreads();
  for (int s = 0; s < 16; s++) {
    if (s < 15) G1_STAGE((s + 1) & 1, (s + 1) * 32);
    const int cur = s & 1;
    bf8v a[10];
#pragma unroll
    for (int mt = 0; mt < 10; mt++)
      a[mt] = *(const bf8v*)(cb + (size_t)(16 * mt) * CC + s * 32);
    bf8v bv[2];
#pragma unroll
    for (int cc = 0; cc < 2; cc++) {
      int row = w * 32 + cc * 16 + m16;
      int slot = q ^ ((row >> 1) & 3);
      bv[cc] = *(const bf8v*)&sB[cur][row * 32 + slot * 8];
    }
#pragma unroll
    for (int mt = 0; mt < 10; mt++) {
      acc[mt][0] = __builtin_amdgcn_mfma_f32_16x16x32_bf16(a[mt], bv[0], acc[mt][0], 0, 0, 0);
      acc[mt][1] = __builtin_amdgcn_mfma_f32_16x16x32_bf16(a[mt], bv[1], acc[mt][1], 0, 0, 0);
    }
    __syncthreads();
  }
  // ---- epilogue: exp in-register, E16/ET16 stores, vvec (no atomics) ----
  float cs0 = 0.f, cs1 = 0.f;
#pragma unroll
  for (int mt = 0; mt < 10; mt++)
#pragma unroll
    for (int r = 0; r < 4; r++) {
      int k = 16 * mt + 4 * q + r;
      bool valid = k < KK;
      float e0 = valid ? __expf(acc[mt][0][r]) : 0.f;
      float e1 = valid ? __expf(acc[mt][1][r]) : 0.f;
      acc[mt][0][r] = e0;
      acc[mt][1][r] = e1;
      cs0 += e0;
      cs1 += e1;
    }
#pragma unroll
  for (int mt = 0; mt < 10; mt++)
#pragma unroll
    for (int r = 0; r < 4; r++) {
      int k = 16 * mt + 4 * q + r;
      size_t row = ((size_t)(b * KP + k)) * HWN + n0 + 32 * w;
      E16[row + m16] = f2b(acc[mt][0][r]);
      E16[row + 16 + m16] = f2b(acc[mt][1][r]);
    }
  const int nA = n0 + 32 * w + m16;
#pragma unroll
  for (int mt = 0; mt < 10; mt++) {
    unsigned lo0 = (unsigned)f2b(acc[mt][0][0]) | ((unsigned)f2b(acc[mt][0][1]) << 16);
    unsigned hi0 = (unsigned)f2b(acc[mt][0][2]) | ((unsigned)f2b(acc[mt][0][3]) << 16);
    unsigned lo1 = (unsigned)f2b(acc[mt][1][0]) | ((unsigned)f2b(acc[mt][1][1]) << 16);
    unsigned hi1 = (unsigned)f2b(acc[mt][1][2]) | ((unsigned)f2b(acc[mt][1][3]) << 16);
    size_t eoff = ((size_t)(b * HWN + nA)) * KP + 16 * mt + 4 * q;
    *(uint2*)&ET16[eoff] = make_uint2(lo0, hi0);
    *(uint2*)&ET16[eoff + (size_t)16 * KP] = make_uint2(lo1, hi1);
  }
  cs0 += __shfl_xor(cs0, 16, 64);
  cs0 += __shfl_xor(cs0, 32, 64);
  cs1 += __shfl_xor(cs1, 16, 64);
  cs1 += __shfl_xor(cs1, 32, 64);
  if (q == 0) {
    vvec[b * HWN + nA] = 1.0f / cs0;
    vvec[b * HWN + nA + 16] = 1.0f / cs1;
  }
}

// ---------------------------------------------------------------------------
// g2: rowsum[b][k] = sum_n E16[b][k][n]  (coalesced stream, no atomics)
// ---------------------------------------------------------------------------
__global__ __launch_bounds__(256) void g2_rowsum(const unsigned short* __restrict__ E16,
                                                 float* __restrict__ rowsum) {
  const int bk = blockIdx.x;
  const int b = bk / KK, k = bk % KK;
  const bf8v* row = (const bf8v*)(E16 + ((size_t)(b * KP + k)) * HWN);
  __shared__ float red[4];
  const int tid = threadIdx.x, lane = tid & 63, w = tid >> 6;
  float s = 0.f;
  for (int i = tid; i < HWN / 8; i += 256) {
    bf8v u = row[i];
#pragma unroll
    for (int j = 0; j < 8; j++) s += b2fs(u[j]);
  }
#pragma unroll
  for (int o = 32; o > 0; o >>= 1) s += __shfl_down(s, o, 64);
  if (lane == 0) red[w] = s;
  __syncthreads();
  if (tid == 0) rowsum[bk] = red[0] + red[1] + red[2] + red[3];
}

// ---------------------------------------------------------------------------
// g3: Scp[b][seg][k][c] = sum_{n in seg} E[k][n]*x16[c][n]  via MFMA.
// (unchanged this round — control for the staging experiment)
// ---------------------------------------------------------------------------
__global__ __launch_bounds__(256) void g3_mfma(const unsigned short* __restrict__ x16,
                                               const unsigned short* __restrict__ E16,
                                               float* __restrict__ Scp) {
  const int cblk = blockIdx.x, seg = blockIdx.y, b = blockIdx.z;
  const int tid = threadIdx.x, w = tid >> 6, L = tid & 63;
  const int q = L >> 4, m16 = L & 15;
  f4v zf = {0.f, 0.f, 0.f, 0.f};
  f4v acc[10][2];
#pragma unroll
  for (int mt = 0; mt < 10; mt++) { acc[mt][0] = zf; acc[mt][1] = zf; }
  const unsigned short* eb = E16 + ((size_t)(b * KP + m16)) * HWN + 8 * q;
  const unsigned short* xb = x16 + ((size_t)(b * CC + cblk * 128 + 32 * w + m16)) * HWN + 8 * q;
  const int ns0 = seg * SEGN;
#pragma unroll 2
  for (int nc0 = ns0; nc0 < ns0 + SEGN; nc0 += 32) {
    bf8v x0 = *(const bf8v*)(xb + nc0);
    bf8v x1 = *(const bf8v*)(xb + (size_t)16 * HWN + nc0);
#pragma unroll
    for (int mt = 0; mt < 10; mt++) {
      bf8v a = *(const bf8v*)(eb + (size_t)(16 * mt) * HWN + nc0);
      acc[mt][0] = __builtin_amdgcn_mfma_f32_16x16x32_bf16(a, x0, acc[mt][0], 0, 0, 0);
      acc[mt][1] = __builtin_amdgcn_mfma_f32_16x16x32_bf16(a, x1, acc[mt][1], 0, 0, 0);
    }
  }
#pragma unroll
  for (int mt = 0; mt < 10; mt++)
#pragma unroll
    for (int cc = 0; cc < 2; cc++)
#pragma unroll
      for (int r = 0; r < 4; r++) {
        int k = 16 * mt + 4 * q + r;
        if (k < KK) {
          int c = cblk * 128 + 32 * w + 16 * cc + m16;
          Scp[(((size_t)(b * NSEG + seg)) * KK + k) * CC + c] = acc[mt][cc][r];
        }
      }
}

// ---------------------------------------------------------------------------
// g5: Sc16[b][kp][c] = bf16( (sum_seg Scp)/rowsum )
// ---------------------------------------------------------------------------
__global__ __launch_bounds__(256) void g5_reduce(const float* __restrict__ Scp,
                                                 const float* __restrict__ rowsum,
                                                 unsigned short* __restrict__ Sc16) {
  const int bk = blockIdx.x;
  const int b = bk / KK, k = bk % KK;
  const float inv = 1.0f / rowsum[bk];
  for (int c = threadIdx.x; c < CC; c += 256) {
    float s = 0.f;
    for (int g = 0; g < NSEG; g++)
      s += Scp[(((size_t)(b * NSEG + g)) * KK + k) * CC + c];
    Sc16[((size_t)b * KP + k) * CC + c] = f2b(s * inv);
  }
}

// ---------------------------------------------------------------------------
// g4b: CWf16[k1][j] = bf16( sum_c cls[k1][c]*Wf[j][c] )  via MFMA
// ---------------------------------------------------------------------------
__global__ __launch_bounds__(256) void g4b_cwf(const unsigned short* __restrict__ cls16,
                                               const unsigned short* __restrict__ Wf16,
                                               unsigned short* __restrict__ CWf16) {
  const int tid = threadIdx.x, w = tid >> 6, L = tid & 63;
  const int q = L >> 4, m16 = L & 15;
  const int j0 = blockIdx.x * 128 + 32 * w;
  f4v zf = {0.f, 0.f, 0.f, 0.f};
  f4v acc[10][2];
#pragma unroll
  for (int mt = 0; mt < 10; mt++) { acc[mt][0] = zf; acc[mt][1] = zf; }
  const unsigned short* ar = cls16 + (size_t)m16 * CC + 8 * q;
  const unsigned short* br = Wf16 + (size_t)(j0 + m16) * CC + 8 * q;
#pragma unroll 2
  for (int c0 = 0; c0 < CC; c0 += 32) {
    bf8v b0 = *(const bf8v*)(br + c0);
    bf8v b1 = *(const bf8v*)(br + (size_t)16 * CC + c0);
#pragma unroll
    for (int mt = 0; mt < 10; mt++) {
      bf8v a = *(const bf8v*)(ar + (size_t)(16 * mt) * CC + c0);
      acc[mt][0] = __builtin_amdgcn_mfma_f32_16x16x32_bf16(a, b0, acc[mt][0], 0, 0, 0);
      acc[mt][1] = __builtin_amdgcn_mfma_f32_16x16x32_bf16(a, b1, acc[mt][1], 0, 0, 0);
    }
  }
#pragma unroll
  for (int mt = 0; mt < 10; mt++)
#pragma unroll
    for (int nc = 0; nc < 2; nc++)
#pragma unroll
      for (int r = 0; r < 4; r++) {
        int k1 = 16 * mt + 4 * q + r;  // rows >=150 come out zero (cls16 pad)
        int j = j0 + 16 * nc + m16;
        CWf16[(size_t)k1 * CC + j] = f2b(acc[mt][nc][r]);
      }
}

// ---------------------------------------------------------------------------
// g4a: AC16[b][k][j] = bf16( cls[k][j] + sum_c Sc16[b,k][c]*Wc16[j][c] )
// ---------------------------------------------------------------------------
__global__ __launch_bounds__(256) void g4a_ac(const unsigned short* __restrict__ Sc16,
                                              const unsigned short* __restrict__ Wc16,
                                              const float* __restrict__ cls,
                                              unsigned short* __restrict__ AC16) {
  const int b = blockIdx.y;
  const int tid = threadIdx.x, w = tid >> 6, L = tid & 63;
  const int q = L >> 4, m16 = L & 15;
  const int j0 = blockIdx.x * 128 + 32 * w;
  f4v zf = {0.f, 0.f, 0.f, 0.f};
  f4v acc[10][2];
#pragma unroll
  for (int mt = 0; mt < 10; mt++) { acc[mt][0] = zf; acc[mt][1] = zf; }
  const unsigned short* ar = Sc16 + ((size_t)b * KP + m16) * CC + 8 * q;
  const unsigned short* br = Wc16 + (size_t)(j0 + m16) * CC + 8 * q;
#pragma unroll 2
  for (int c0 = 0; c0 < CC; c0 += 32) {
    bf8v b0 = *(const bf8v*)(br + c0);
    bf8v b1 = *(const bf8v*)(br + (size_t)16 * CC + c0);
#pragma unroll
    for (int mt = 0; mt < 10; mt++) {
      bf8v a = *(const bf8v*)(ar + (size_t)(16 * mt) * CC + c0);
      acc[mt][0] = __builtin_amdgcn_mfma_f32_16x16x32_bf16(a, b0, acc[mt][0], 0, 0, 0);
      acc[mt][1] = __builtin_amdgcn_mfma_f32_16x16x32_bf16(a, b1, acc[mt][1], 0, 0, 0);
    }
  }
#pragma unroll
  for (int mt = 0; mt < 10; mt++)
#pragma unroll
    for (int nc = 0; nc < 2; nc++)
#pragma unroll
      for (int r = 0; r < 4; r++) {
        int k = 16 * mt + 4 * q + r;
        if (k < KK) {
          int j = j0 + 16 * nc + m16;
          AC16[((size_t)b * KP + k) * CC + j] = f2b(cls[k * CC + j] + acc[mt][nc][r]);
        }
      }
}

// ---------------------------------------------------------------------------
// g4c: MT16[b][k2][k1] = bf16( sum_c AC16[b,k2][c]*CWf16[k1][c] )  via MFMA
// ---------------------------------------------------------------------------
__global__ __launch_bounds__(256) void g4c_m(const unsigned short* __restrict__ AC16,
                                             const unsigned short* __restrict__ CWf16,
                                             unsigned short* __restrict__ MT16) {
  const int b = blockIdx.y;
  const int tid = threadIdx.x, w = tid >> 6, L = tid & 63;
  const int q = L >> 4, m16 = L & 15;
  const int k1t = blockIdx.x * 64 + 16 * w;
  f4v zf = {0.f, 0.f, 0.f, 0.f};
  f4v acc[10];
#pragma unroll
  for (int mt = 0; mt < 10; mt++) acc[mt] = zf;
  const unsigned short* ar = AC16 + ((size_t)b * KP + m16) * CC + 8 * q;
  const unsigned short* br = CWf16 + (size_t)(k1t + m16) * CC + 8 * q;
#pragma unroll 2
  for (int c0 = 0; c0 < CC; c0 += 32) {
    bf8v bb = *(const bf8v*)(br + c0);
#pragma unroll
    for (int mt = 0; mt < 10; mt++) {
      bf8v a = *(const bf8v*)(ar + (size_t)(16 * mt) * CC + c0);
      acc[mt] = __builtin_amdgcn_mfma_f32_16x16x32_bf16(a, bb, acc[mt], 0, 0, 0);
    }
  }
  const int k1 = k1t + m16;
#pragma unroll
  for (int mt = 0; mt < 10; mt++)
#pragma unroll
    for (int r = 0; r < 4; r++) {
      int k2 = 16 * mt + 4 * q + r;
      if (k1 < KK) MT16[((size_t)b * KP + k2) * KP + k1] = f2b(acc[mt][r]);
    }
}

// ---------------------------------------------------------------------------
// g6: masks[k][n] = v[n]*(sum_k' MT'[k][k']*ET[n][k']) + sum_c AC[k][c]*xT[n][c]
//     part 2 direct-global (K=160), part 1 LDS-staged like g1. LN epilogue.
// ---------------------------------------------------------------------------
__global__ __launch_bounds__(256) void g6_mfma(
    const unsigned short* __restrict__ xT, const unsigned short* __restrict__ ET,
    const float* __restrict__ vvec, const unsigned short* __restrict__ AC16,
    const unsigned short* __restrict__ MT16, const float* __restrict__ gamma,
    const float* __restrict__ beta, float* __restrict__ out) {
  __shared__ unsigned short sB[2][128 * 32];
  const int n0 = blockIdx.x * 128, b = blockIdx.y;
  const int tid = threadIdx.x, w = tid >> 6, L = tid & 63;
  const int q = L >> 4, m16 = L & 15;
  f4v zf = {0.f, 0.f, 0.f, 0.f};
  f4v acc[10][2];
#pragma unroll
  for (int mt = 0; mt < 10; mt++) { acc[mt][0] = zf; acc[mt][1] = zf; }

  const int sr0 = w * 32 + (L >> 2);
  const int sch = L & 3;
  const unsigned short* xbase = xT + (size_t)(b * HWN + n0) * CC;
#define G6_STAGE(buf, c0)                                                      \
  {                                                                            \
    _Pragma("unroll") for (int j = 0; j < 2; j++) {                            \
      int row = sr0 + j * 16;                                                  \
      int ch = sch ^ ((row >> 1) & 3);                                         \
      gload16(xbase + (size_t)row * CC + (c0) + ch * 8,                        \
              &sB[buf][(w * 32 + j * 16) * 32]);                               \
    }                                                                          \
  }
  // prefetch first x-tile under part-2's compute
  G6_STAGE(0, 0);

  // ---- part 2: acc = sum_k' MT'[k][k'] * ET[n][k'] ----
  const unsigned short* et0 = ET + ((size_t)(b * HWN + n0 + 32 * w + m16)) * KP + 8 * q;
  const unsigned short* et1 = et0 + 16 * KP;
  const unsigned short* mb = MT16 + (size_t)b * KP * KP + (size_t)m16 * KP + 8 * q;
#pragma unroll
  for (int kc = 0; kc < KP; kc += 32) {
    bf8v b0 = *(const bf8v*)(et0 + kc);
    bf8v b1 = *(const bf8v*)(et1 + kc);
#pragma unroll
    for (int mt = 0; mt < 10; mt++) {
      bf8v a = *(const bf8v*)(mb + (size_t)(16 * mt) * KP + kc);
      acc[mt][0] = __builtin_amdgcn_mfma_f32_16x16x32_bf16(a, b0, acc[mt][0], 0, 0, 0);
      acc[mt][1] = __builtin_amdgcn_mfma_f32_16x16x32_bf16(a, b1, acc[mt][1], 0, 0, 0);
    }
  }
  const float v0 = vvec[b * HWN + n0 + 32 * w + m16];
  const float v1 = vvec[b * HWN + n0 + 32 * w + 16 + m16];
#pragma unroll
  for (int mt = 0; mt < 10; mt++)
#pragma unroll
    for (int r = 0; r < 4; r++) {
      acc[mt][0][r] *= v0;
      acc[mt][1][r] *= v1;
    }

  // ---- part 1: acc += sum_c AC[k][c]*xT[n][c]  (LDS-staged B) ----
  const unsigned short* ab = AC16 + (size_t)b * KP * CC + (size_t)m16 * CC + 8 * q;
  __syncthreads();
  for (int s = 0; s < 16; s++) {
    if (s < 15) G6_STAGE((s + 1) & 1, (s + 1) * 32);
    const int cur = s & 1;
    bf8v a[10];
#pragma unroll
    for (int mt = 0; mt < 10; mt++)
      a[mt] = *(const bf8v*)(ab + (size_t)(16 * mt) * CC + s * 32);
    bf8v bv[2];
#pragma unroll
    for (int cc = 0; cc < 2; cc++) {
      int row = w * 32 + cc * 16 + m16;
      int slot = q ^ ((row >> 1) & 3);
      bv[cc] = *(const bf8v*)&sB[cur][row * 32 + slot * 8];
    }
#pragma unroll
    for (int mt = 0; mt < 10; mt++) {
      acc[mt][0] = __builtin_amdgcn_mfma_f32_16x16x32_bf16(a[mt], bv[0], acc[mt][0], 0, 0, 0);
      acc[mt][1] = __builtin_amdgcn_mfma_f32_16x16x32_bf16(a[mt], bv[1], acc[mt][1], 0, 0, 0);
    }
    __syncthreads();
  }

  // ---- LayerNorm over k per n (pad rows are exactly zero) ----
  float s1[2] = {0.f, 0.f}, s2[2] = {0.f, 0.f};
#pragma unroll
  for (int mt = 0; mt < 10; mt++)
#pragma unroll
    for (int r = 0; r < 4; r++)
#pragma unroll
      for (int nc = 0; nc < 2; nc++) {
        float a = acc[mt][nc][r];
        s1[nc] += a;
        s2[nc] += a * a;
      }
#pragma unroll
  for (int nc = 0; nc < 2; nc++) {
    s1[nc] += __shfl_xor(s1[nc], 16, 64);
    s1[nc] += __shfl_xor(s1[nc], 32, 64);
    s2[nc] += __shfl_xor(s2[nc], 16, 64);
    s2[nc] += __shfl_xor(s2[nc], 32, 64);
  }
  float mu[2], inv[2];
#pragma unroll
  for (int nc = 0; nc < 2; nc++) {
    mu[nc] = s1[nc] * (1.0f / KK);
    float var = s2[nc] * (1.0f / KK) - mu[nc] * mu[nc];
    inv[nc] = rsqrtf(var + 1e-5f);
  }
#pragma unroll
  for (int mt = 0; mt < 10; mt++)
#pragma unroll
    for (int r = 0; r < 4; r++) {
      int k = 16 * mt + 4 * q + r;
      if (k < KK) {
        float g = gamma[k], be = beta[k];
        size_t row = (size_t)(b * KK + k) * HWN + n0 + 32 * w;
        out[row + m16] = (acc[mt][0][r] - mu[0]) * inv[0] * g + be;
        out[row + 16 + m16] = (acc[mt][1][r] - mu[1]) * inv[1] * g + be;
      }
    }
}

// ---------------------------------------------------------------------------
extern "C" void kernel_launch(void* const* d_in, const int* in_sizes, int n_in,
                              void* d_out, int out_size, void* d_ws, size_t ws_size,
                              hipStream_t stream) {
  const float* x = (const float*)d_in[0];
  const float* cls = (const float*)d_in[1];
  const float* Wc = (const float*)d_in[2];
  const float* Wf = (const float*)d_in[3];
  const float* gam = (const float*)d_in[4];
  const float* bet = (const float*)d_in[5];
  float* out = (float*)d_out;

  char* p = (char*)d_ws;
  auto alloc = [&](size_t bytes) {
    char* r = p;
    p += (bytes + 255) & ~(size_t)255;
    return r;
  };
  unsigned short* xT16 = (unsigned short*)alloc((size_t)BB * HWN * CC * 2);
  unsigned short* x16 = (unsigned short*)alloc((size_t)BB * CC * HWN * 2);
  unsigned short* E16 = (unsigned short*)alloc((size_t)BB * KP * HWN * 2);
  unsigned short* ET16 = (unsigned short*)alloc((size_t)BB * HWN * KP * 2);
  float* Scp = (float*)alloc((size_t)BB * NSEG * KK * CC * 4);
  unsigned short* Sc16 = (unsigned short*)alloc((size_t)BB * KP * CC * 2);
  unsigned short* AC16 = (unsigned short*)alloc((size_t)BB * KP * CC * 2);
  unsigned short* CWf16 = (unsigned short*)alloc((size_t)192 * CC * 2);
  unsigned short* cls16 = (unsigned short*)alloc((size_t)KP * CC * 2);
  unsigned short* Wc16 = (unsigned short*)alloc((size_t)CC * CC * 2);
  unsigned short* Wf16 = (unsigned short*)alloc((size_t)CC * CC * 2);
  unsigned short* MT16 = (unsigned short*)alloc((size_t)BB * KP * KP * 2);
  float* rowsum = (float*)alloc(BB * KK * 4);
  float* vvec = (float*)alloc((size_t)BB * HWN * 4);

  t0_prep<<<dim3((CC * CC + 255) / 256), 256, 0, stream>>>(cls, Wc, Wf, cls16, Wc16,
                                                           Wf16, MT16, AC16);
  t1_transpose<<<dim3(HWN / 64, CC / 32, BB), 256, 0, stream>>>(x, xT16, x16);
  g1_mfma<<<dim3(HWN / 128, BB), 256, 0, stream>>>(xT16, cls16, E16, ET16, vvec);
  g2_rowsum<<<dim3(BB * KK), 256, 0, stream>>>(E16, rowsum);
  g4b_cwf<<<dim3(CC / 128), 256, 0, stream>>>(cls16, Wf16, CWf16);
  g3_mfma<<<dim3(CC / 128, NSEG, BB), 256, 0, stream>>>(x16, E16, Scp);
  g5_reduce<<<dim3(BB * KK), 256, 0, stream>>>(Scp, rowsum, Sc16);
  g4a_ac<<<dim3(CC / 128, BB), 256, 0, stream>>>(Sc16, Wc16, cls, AC16);
  g4c_m<<<dim3(3, BB), 256, 0, stream>>>(AC16, CWf16, MT16);
  g6_mfma<<<dim3(HWN / 128, BB), 256, 0, stream>>>(xT16, ET16, vvec, AC16, MT16,
                                                   gam, bet, out);
}

// Round 5
// 907.032 us; speedup vs baseline: 1.0419x; 1.0419x over previous
//
#include <hip/hip_runtime.h>
#include <math.h>

#define BB 8
#define CC 512
#define HWN 16384
#define KK 150
#define KP 160
#define NSEG 16
#define SEGN (HWN / NSEG)  // 1024

typedef short bf8v __attribute__((ext_vector_type(8)));
typedef float f4v __attribute__((ext_vector_type(4)));

static __device__ inline unsigned short f2b(float f) {
  unsigned u = __float_as_uint(f);
  u += 0x7fffu + ((u >> 16) & 1u);
  return (unsigned short)(u >> 16);
}
static __device__ inline float b2f(unsigned short s) {
  return __uint_as_float(((unsigned)s) << 16);
}
static __device__ inline float b2fs(short s) { return b2f((unsigned short)s); }

// ---------------------------------------------------------------------------
// t0: cls16 [160][512] (rows>=150 zero), zero MT16, zero AC16 pad rows,
//     Wc16/Wf16 bf16 conversions.
// ---------------------------------------------------------------------------
__global__ __launch_bounds__(256) void t0_prep(const float* __restrict__ cls,
                                               const float* __restrict__ Wc,
                                               const float* __restrict__ Wf,
                                               unsigned short* __restrict__ cls16,
                                               unsigned short* __restrict__ Wc16,
                                               unsigned short* __restrict__ Wf16,
                                               unsigned short* __restrict__ MT16,
                                               unsigned short* __restrict__ AC16) {
  int i = blockIdx.x * 256 + threadIdx.x;
  if (i < KP * CC) {
    int k = i >> 9, c = i & 511;
    cls16[i] = (k < KK) ? f2b(cls[k * CC + c]) : 0;
  }
  if (i < BB * KP * KP) MT16[i] = 0;
  if (i < BB * (KP - KK) * CC) {
    int b = i / ((KP - KK) * CC);
    int r = i % ((KP - KK) * CC);
    int k = KK + (r >> 9);
    int c = r & 511;
    AC16[((size_t)b * KP + k) * CC + c] = 0;
  }
  if (i < CC * CC) {
    Wc16[i] = f2b(Wc[i]);
    Wf16[i] = f2b(Wf[i]);
  }
}

// ---------------------------------------------------------------------------
// t1: x [b][c][n] fp32 -> xT16 [b][n][c] bf16 (LDS transpose) + x16 [b][c][n]
// Vectorized: float4 global loads, 8B ushort4 stores both directions.
// ---------------------------------------------------------------------------
__global__ __launch_bounds__(256) void t1_transpose(const float* __restrict__ x,
                                                    unsigned short* __restrict__ xT,
                                                    unsigned short* __restrict__ x16) {
  __shared__ float ts[32][65];
  const int n0 = blockIdx.x * 64, c0 = blockIdx.y * 32, b = blockIdx.z;
  const int tid = threadIdx.x;
  const float* xb = x + (size_t)b * CC * HWN;
  unsigned short* x16o = x16 + (size_t)b * CC * HWN;
#pragma unroll
  for (int i = 0; i < 2; i++) {
    int e = tid + i * 256;  // 0..511
    int c = e >> 4, n4 = (e & 15) * 4;
    float4 v = *(const float4*)&xb[(size_t)(c0 + c) * HWN + n0 + n4];
    ts[c][n4] = v.x;
    ts[c][n4 + 1] = v.y;
    ts[c][n4 + 2] = v.z;
    ts[c][n4 + 3] = v.w;
    ushort4 pk;
    pk.x = f2b(v.x);
    pk.y = f2b(v.y);
    pk.z = f2b(v.z);
    pk.w = f2b(v.w);
    *(ushort4*)&x16o[(size_t)(c0 + c) * HWN + n0 + n4] = pk;
  }
  __syncthreads();
  unsigned short* xo = xT + (size_t)b * HWN * CC;
#pragma unroll
  for (int i = 0; i < 2; i++) {
    int e = tid + i * 256;  // 0..511
    int cg = e & 7, n = e >> 3;
    ushort4 pk;
    pk.x = f2b(ts[4 * cg][n]);
    pk.y = f2b(ts[4 * cg + 1][n]);
    pk.z = f2b(ts[4 * cg + 2][n]);
    pk.w = f2b(ts[4 * cg + 3][n]);
    *(ushort4*)&xo[(size_t)(n0 + n) * CC + c0 + 4 * cg] = pk;
  }
}

// ---------------------------------------------------------------------------
// g1: A[k][n] = sum_c cls[k][c]*x[c][n] via MFMA, direct loads, NO LDS.
// B (xT16, the HBM stream) is explicitly register-double-buffered: next
// step's fragments are issued before this step's MFMAs, so the in-order
// vmcnt wait for A (L2-resident cls16) gives B a full step to land.
// Epilogue: E16 + ET16 + vvec (identical math to round 2).
// ---------------------------------------------------------------------------
__global__ __launch_bounds__(256) void g1_mfma(const unsigned short* __restrict__ xT,
                                               const unsigned short* __restrict__ cls16,
                                               unsigned short* __restrict__ E16,
                                               unsigned short* __restrict__ ET16,
                                               float* __restrict__ vvec) {
  const int n0 = blockIdx.x * 128, b = blockIdx.y;
  const int tid = threadIdx.x, w = tid >> 6, L = tid & 63;
  const int q = L >> 4, m16 = L & 15;
  f4v zf = {0.f, 0.f, 0.f, 0.f};
  f4v acc[10][2];
#pragma unroll
  for (int mt = 0; mt < 10; mt++) { acc[mt][0] = zf; acc[mt][1] = zf; }
  const unsigned short* xr0 = xT + ((size_t)(b * HWN + n0 + 32 * w + m16)) * CC + 8 * q;
  const unsigned short* xr1 = xr0 + 16 * CC;
  const unsigned short* cb = cls16 + (size_t)m16 * CC + 8 * q;
  bf8v b0 = *(const bf8v*)(xr0);
  bf8v b1 = *(const bf8v*)(xr1);
#pragma unroll 2
  for (int s = 0; s < 16; s++) {
    const int cn = ((s + 1) & 15) * 32;  // wraps at s=15: redundant, unused
    bf8v p0 = *(const bf8v*)(xr0 + cn);
    bf8v p1 = *(const bf8v*)(xr1 + cn);
    bf8v a[10];
#pragma unroll
    for (int mt = 0; mt < 10; mt++)
      a[mt] = *(const bf8v*)(cb + (size_t)(16 * mt) * CC + s * 32);
#pragma unroll
    for (int mt = 0; mt < 10; mt++) {
      acc[mt][0] = __builtin_amdgcn_mfma_f32_16x16x32_bf16(a[mt], b0, acc[mt][0], 0, 0, 0);
      acc[mt][1] = __builtin_amdgcn_mfma_f32_16x16x32_bf16(a[mt], b1, acc[mt][1], 0, 0, 0);
    }
    b0 = p0;
    b1 = p1;
  }
  // exp in-register (overwrite acc), accumulate column sums
  float cs0 = 0.f, cs1 = 0.f;
#pragma unroll
  for (int mt = 0; mt < 10; mt++)
#pragma unroll
    for (int r = 0; r < 4; r++) {
      int k = 16 * mt + 4 * q + r;
      bool valid = k < KK;
      float e0 = valid ? __expf(acc[mt][0][r]) : 0.f;
      float e1 = valid ? __expf(acc[mt][1][r]) : 0.f;
      acc[mt][0][r] = e0;
      acc[mt][1][r] = e1;
      cs0 += e0;
      cs1 += e1;
    }
  // E16 row-major stores (tight, store-only loop)
#pragma unroll
  for (int mt = 0; mt < 10; mt++)
#pragma unroll
    for (int r = 0; r < 4; r++) {
      int k = 16 * mt + 4 * q + r;
      size_t row = ((size_t)(b * KP + k)) * HWN + n0 + 32 * w;
      E16[row + m16] = f2b(acc[mt][0][r]);
      E16[row + 16 + m16] = f2b(acc[mt][1][r]);
    }
  // ET16 packed stores (8B per store)
  const int nA = n0 + 32 * w + m16;
#pragma unroll
  for (int mt = 0; mt < 10; mt++) {
    unsigned lo0 = (unsigned)f2b(acc[mt][0][0]) | ((unsigned)f2b(acc[mt][0][1]) << 16);
    unsigned hi0 = (unsigned)f2b(acc[mt][0][2]) | ((unsigned)f2b(acc[mt][0][3]) << 16);
    unsigned lo1 = (unsigned)f2b(acc[mt][1][0]) | ((unsigned)f2b(acc[mt][1][1]) << 16);
    unsigned hi1 = (unsigned)f2b(acc[mt][1][2]) | ((unsigned)f2b(acc[mt][1][3]) << 16);
    size_t eoff = ((size_t)(b * HWN + nA)) * KP + 16 * mt + 4 * q;
    *(uint2*)&ET16[eoff] = make_uint2(lo0, hi0);
    *(uint2*)&ET16[eoff + (size_t)16 * KP] = make_uint2(lo1, hi1);
  }
  // column softmax denominators (4 shuffles total, at the very end)
  cs0 += __shfl_xor(cs0, 16, 64);
  cs0 += __shfl_xor(cs0, 32, 64);
  cs1 += __shfl_xor(cs1, 16, 64);
  cs1 += __shfl_xor(cs1, 32, 64);
  if (q == 0) {
    vvec[b * HWN + nA] = 1.0f / cs0;
    vvec[b * HWN + nA + 16] = 1.0f / cs1;
  }
}

// ---------------------------------------------------------------------------
// g2: rowsum[b][k] = sum_n E16[b][k][n]  (coalesced stream, no atomics)
// ---------------------------------------------------------------------------
__global__ __launch_bounds__(256) void g2_rowsum(const unsigned short* __restrict__ E16,
                                                 float* __restrict__ rowsum) {
  const int bk = blockIdx.x;
  const int b = bk / KK, k = bk % KK;
  const bf8v* row = (const bf8v*)(E16 + ((size_t)(b * KP + k)) * HWN);
  __shared__ float red[4];
  const int tid = threadIdx.x, lane = tid & 63, w = tid >> 6;
  float s = 0.f;
  for (int i = tid; i < HWN / 8; i += 256) {
    bf8v u = row[i];
#pragma unroll
    for (int j = 0; j < 8; j++) s += b2fs(u[j]);
  }
#pragma unroll
  for (int o = 32; o > 0; o >>= 1) s += __shfl_down(s, o, 64);
  if (lane == 0) red[w] = s;
  __syncthreads();
  if (tid == 0) rowsum[bk] = red[0] + red[1] + red[2] + red[3];
}

// ---------------------------------------------------------------------------
// g3: Scp[b][seg][k][c] = sum_{n in seg} E[k][n]*x16[c][n]  via MFMA.
// Both operands (E16, x16) are streams -> full 12-fragment register
// double-buffer (prefetch distance 1), no LDS, no barriers.
// ---------------------------------------------------------------------------
__global__ __launch_bounds__(256) void g3_mfma(const unsigned short* __restrict__ x16,
                                               const unsigned short* __restrict__ E16,
                                               float* __restrict__ Scp) {
  const int cblk = blockIdx.x, seg = blockIdx.y, b = blockIdx.z;
  const int tid = threadIdx.x, w = tid >> 6, L = tid & 63;
  const int q = L >> 4, m16 = L & 15;
  f4v zf = {0.f, 0.f, 0.f, 0.f};
  f4v acc[10][2];
#pragma unroll
  for (int mt = 0; mt < 10; mt++) { acc[mt][0] = zf; acc[mt][1] = zf; }
  const unsigned short* eb = E16 + ((size_t)(b * KP + m16)) * HWN + 8 * q;
  const unsigned short* xb = x16 + ((size_t)(b * CC + cblk * 128 + 32 * w + m16)) * HWN + 8 * q;
  const int ns0 = seg * SEGN;
  bf8v aC[10], x0, x1;
#pragma unroll
  for (int mt = 0; mt < 10; mt++) aC[mt] = *(const bf8v*)(eb + (size_t)(16 * mt) * HWN + ns0);
  x0 = *(const bf8v*)(xb + ns0);
  x1 = *(const bf8v*)(xb + (size_t)16 * HWN + ns0);
#pragma unroll 2
  for (int i = 0; i < SEGN / 32; i++) {
    const int nn = ns0 + (((i + 1) & (SEGN / 32 - 1)) * 32);  // wraps at last
    bf8v aN[10], p0, p1;
#pragma unroll
    for (int mt = 0; mt < 10; mt++)
      aN[mt] = *(const bf8v*)(eb + (size_t)(16 * mt) * HWN + nn);
    p0 = *(const bf8v*)(xb + nn);
    p1 = *(const bf8v*)(xb + (size_t)16 * HWN + nn);
#pragma unroll
    for (int mt = 0; mt < 10; mt++) {
      acc[mt][0] = __builtin_amdgcn_mfma_f32_16x16x32_bf16(aC[mt], x0, acc[mt][0], 0, 0, 0);
      acc[mt][1] = __builtin_amdgcn_mfma_f32_16x16x32_bf16(aC[mt], x1, acc[mt][1], 0, 0, 0);
    }
#pragma unroll
    for (int mt = 0; mt < 10; mt++) aC[mt] = aN[mt];
    x0 = p0;
    x1 = p1;
  }
#pragma unroll
  for (int mt = 0; mt < 10; mt++)
#pragma unroll
    for (int cc = 0; cc < 2; cc++)
#pragma unroll
      for (int r = 0; r < 4; r++) {
        int k = 16 * mt + 4 * q + r;
        if (k < KK) {
          int c = cblk * 128 + 32 * w + 16 * cc + m16;
          Scp[(((size_t)(b * NSEG + seg)) * KK + k) * CC + c] = acc[mt][cc][r];
        }
      }
}

// ---------------------------------------------------------------------------
// g5: Sc16[b][kp][c] = bf16( (sum_seg Scp)/rowsum )
// ---------------------------------------------------------------------------
__global__ __launch_bounds__(256) void g5_reduce(const float* __restrict__ Scp,
                                                 const float* __restrict__ rowsum,
                                                 unsigned short* __restrict__ Sc16) {
  const int bk = blockIdx.x;
  const int b = bk / KK, k = bk % KK;
  const float inv = 1.0f / rowsum[bk];
  for (int c = threadIdx.x; c < CC; c += 256) {
    float s = 0.f;
    for (int g = 0; g < NSEG; g++)
      s += Scp[(((size_t)(b * NSEG + g)) * KK + k) * CC + c];
    Sc16[((size_t)b * KP + k) * CC + c] = f2b(s * inv);
  }
}

// ---------------------------------------------------------------------------
// g4b: CWf16[k1][j] = bf16( sum_c cls[k1][c]*Wf[j][c] )  via MFMA
// ---------------------------------------------------------------------------
__global__ __launch_bounds__(256) void g4b_cwf(const unsigned short* __restrict__ cls16,
                                               const unsigned short* __restrict__ Wf16,
                                               unsigned short* __restrict__ CWf16) {
  const int tid = threadIdx.x, w = tid >> 6, L = tid & 63;
  const int q = L >> 4, m16 = L & 15;
  const int j0 = blockIdx.x * 128 + 32 * w;
  f4v zf = {0.f, 0.f, 0.f, 0.f};
  f4v acc[10][2];
#pragma unroll
  for (int mt = 0; mt < 10; mt++) { acc[mt][0] = zf; acc[mt][1] = zf; }
  const unsigned short* ar = cls16 + (size_t)m16 * CC + 8 * q;
  const unsigned short* br = Wf16 + (size_t)(j0 + m16) * CC + 8 * q;
#pragma unroll 2
  for (int c0 = 0; c0 < CC; c0 += 32) {
    bf8v b0 = *(const bf8v*)(br + c0);
    bf8v b1 = *(const bf8v*)(br + (size_t)16 * CC + c0);
#pragma unroll
    for (int mt = 0; mt < 10; mt++) {
      bf8v a = *(const bf8v*)(ar + (size_t)(16 * mt) * CC + c0);
      acc[mt][0] = __builtin_amdgcn_mfma_f32_16x16x32_bf16(a, b0, acc[mt][0], 0, 0, 0);
      acc[mt][1] = __builtin_amdgcn_mfma_f32_16x16x32_bf16(a, b1, acc[mt][1], 0, 0, 0);
    }
  }
#pragma unroll
  for (int mt = 0; mt < 10; mt++)
#pragma unroll
    for (int nc = 0; nc < 2; nc++)
#pragma unroll
      for (int r = 0; r < 4; r++) {
        int k1 = 16 * mt + 4 * q + r;  // rows >=150 come out zero (cls16 pad)
        int j = j0 + 16 * nc + m16;
        CWf16[(size_t)k1 * CC + j] = f2b(acc[mt][nc][r]);
      }
}

// ---------------------------------------------------------------------------
// g4a: AC16[b][k][j] = bf16( cls[k][j] + sum_c Sc16[b,k][c]*Wc16[j][c] )
// ---------------------------------------------------------------------------
__global__ __launch_bounds__(256) void g4a_ac(const unsigned short* __restrict__ Sc16,
                                              const unsigned short* __restrict__ Wc16,
                                              const float* __restrict__ cls,
                                              unsigned short* __restrict__ AC16) {
  const int b = blockIdx.y;
  const int tid = threadIdx.x, w = tid >> 6, L = tid & 63;
  const int q = L >> 4, m16 = L & 15;
  const int j0 = blockIdx.x * 128 + 32 * w;
  f4v zf = {0.f, 0.f, 0.f, 0.f};
  f4v acc[10][2];
#pragma unroll
  for (int mt = 0; mt < 10; mt++) { acc[mt][0] = zf; acc[mt][1] = zf; }
  const unsigned short* ar = Sc16 + ((size_t)b * KP + m16) * CC + 8 * q;
  const unsigned short* br = Wc16 + (size_t)(j0 + m16) * CC + 8 * q;
#pragma unroll 2
  for (int c0 = 0; c0 < CC; c0 += 32) {
    bf8v b0 = *(const bf8v*)(br + c0);
    bf8v b1 = *(const bf8v*)(br + (size_t)16 * CC + c0);
#pragma unroll
    for (int mt = 0; mt < 10; mt++) {
      bf8v a = *(const bf8v*)(ar + (size_t)(16 * mt) * CC + c0);
      acc[mt][0] = __builtin_amdgcn_mfma_f32_16x16x32_bf16(a, b0, acc[mt][0], 0, 0, 0);
      acc[mt][1] = __builtin_amdgcn_mfma_f32_16x16x32_bf16(a, b1, acc[mt][1], 0, 0, 0);
    }
  }
#pragma unroll
  for (int mt = 0; mt < 10; mt++)
#pragma unroll
    for (int nc = 0; nc < 2; nc++)
#pragma unroll
      for (int r = 0; r < 4; r++) {
        int k = 16 * mt + 4 * q + r;
        if (k < KK) {
          int j = j0 + 16 * nc + m16;
          AC16[((size_t)b * KP + k) * CC + j] = f2b(cls[k * CC + j] + acc[mt][nc][r]);
        }
      }
}

// ---------------------------------------------------------------------------
// g4c: MT16[b][k2][k1] = bf16( sum_c AC16[b,k2][c]*CWf16[k1][c] )  via MFMA
// ---------------------------------------------------------------------------
__global__ __launch_bounds__(256) void g4c_m(const unsigned short* __restrict__ AC16,
                                             const unsigned short* __restrict__ CWf16,
                                             unsigned short* __restrict__ MT16) {
  const int b = blockIdx.y;
  const int tid = threadIdx.x, w = tid >> 6, L = tid & 63;
  const int q = L >> 4, m16 = L & 15;
  const int k1t = blockIdx.x * 64 + 16 * w;
  f4v zf = {0.f, 0.f, 0.f, 0.f};
  f4v acc[10];
#pragma unroll
  for (int mt = 0; mt < 10; mt++) acc[mt] = zf;
  const unsigned short* ar = AC16 + ((size_t)b * KP + m16) * CC + 8 * q;
  const unsigned short* br = CWf16 + (size_t)(k1t + m16) * CC + 8 * q;
#pragma unroll 2
  for (int c0 = 0; c0 < CC; c0 += 32) {
    bf8v bb = *(const bf8v*)(br + c0);
#pragma unroll
    for (int mt = 0; mt < 10; mt++) {
      bf8v a = *(const bf8v*)(ar + (size_t)(16 * mt) * CC + c0);
      acc[mt] = __builtin_amdgcn_mfma_f32_16x16x32_bf16(a, bb, acc[mt], 0, 0, 0);
    }
  }
  const int k1 = k1t + m16;
#pragma unroll
  for (int mt = 0; mt < 10; mt++)
#pragma unroll
    for (int r = 0; r < 4; r++) {
      int k2 = 16 * mt + 4 * q + r;
      if (k1 < KK) MT16[((size_t)b * KP + k2) * KP + k1] = f2b(acc[mt][r]);
    }
}

// ---------------------------------------------------------------------------
// g6: masks[k][n] = v[n]*(sum_k' MT'[k][k']*ET[n][k']) + sum_c AC[k][c]*xT[n][c]
//     then LayerNorm over k.  Part-1 B-stream register-double-buffered.
// ---------------------------------------------------------------------------
__global__ __launch_bounds__(256) void g6_mfma(
    const unsigned short* __restrict__ xT, const unsigned short* __restrict__ ET,
    const float* __restrict__ vvec, const unsigned short* __restrict__ AC16,
    const unsigned short* __restrict__ MT16, const float* __restrict__ gamma,
    const float* __restrict__ beta, float* __restrict__ out) {
  const int n0 = blockIdx.x * 128, b = blockIdx.y;
  const int tid = threadIdx.x, w = tid >> 6, L = tid & 63;
  const int q = L >> 4, m16 = L & 15;
  f4v zf = {0.f, 0.f, 0.f, 0.f};
  f4v acc[10][2];
#pragma unroll
  for (int mt = 0; mt < 10; mt++) { acc[mt][0] = zf; acc[mt][1] = zf; }

  // ---- part 2: acc = sum_k' MT'[k][k'] * ET[n][k'] ----
  const unsigned short* et0 = ET + ((size_t)(b * HWN + n0 + 32 * w + m16)) * KP + 8 * q;
  const unsigned short* et1 = et0 + 16 * KP;
  const unsigned short* mb = MT16 + (size_t)b * KP * KP + (size_t)m16 * KP + 8 * q;
#pragma unroll
  for (int kc = 0; kc < KP; kc += 32) {
    bf8v b0 = *(const bf8v*)(et0 + kc);
    bf8v b1 = *(const bf8v*)(et1 + kc);
#pragma unroll
    for (int mt = 0; mt < 10; mt++) {
      bf8v a = *(const bf8v*)(mb + (size_t)(16 * mt) * KP + kc);
      acc[mt][0] = __builtin_amdgcn_mfma_f32_16x16x32_bf16(a, b0, acc[mt][0], 0, 0, 0);
      acc[mt][1] = __builtin_amdgcn_mfma_f32_16x16x32_bf16(a, b1, acc[mt][1], 0, 0, 0);
    }
  }
  const float v0 = vvec[b * HWN + n0 + 32 * w + m16];
  const float v1 = vvec[b * HWN + n0 + 32 * w + 16 + m16];
#pragma unroll
  for (int mt = 0; mt < 10; mt++)
#pragma unroll
    for (int r = 0; r < 4; r++) {
      acc[mt][0][r] *= v0;
      acc[mt][1][r] *= v1;
    }

  // ---- part 1: acc += sum_c AC[k][c]*xT[n][c]  (B double-buffered) ----
  const unsigned short* xr0 = xT + ((size_t)(b * HWN + n0 + 32 * w + m16)) * CC + 8 * q;
  const unsigned short* xr1 = xr0 + 16 * CC;
  const unsigned short* ab = AC16 + (size_t)b * KP * CC + (size_t)m16 * CC + 8 * q;
  bf8v b0 = *(const bf8v*)(xr0);
  bf8v b1 = *(const bf8v*)(xr1);
#pragma unroll 2
  for (int s = 0; s < 16; s++) {
    const int cn = ((s + 1) & 15) * 32;
    bf8v p0 = *(const bf8v*)(xr0 + cn);
    bf8v p1 = *(const bf8v*)(xr1 + cn);
    bf8v a[10];
#pragma unroll
    for (int mt = 0; mt < 10; mt++)
      a[mt] = *(const bf8v*)(ab + (size_t)(16 * mt) * CC + s * 32);
#pragma unroll
    for (int mt = 0; mt < 10; mt++) {
      acc[mt][0] = __builtin_amdgcn_mfma_f32_16x16x32_bf16(a[mt], b0, acc[mt][0], 0, 0, 0);
      acc[mt][1] = __builtin_amdgcn_mfma_f32_16x16x32_bf16(a[mt], b1, acc[mt][1], 0, 0, 0);
    }
    b0 = p0;
    b1 = p1;
  }

  // ---- LayerNorm over k per n (pad rows are exactly zero) ----
  float s1[2] = {0.f, 0.f}, s2[2] = {0.f, 0.f};
#pragma unroll
  for (int mt = 0; mt < 10; mt++)
#pragma unroll
    for (int r = 0; r < 4; r++)
#pragma unroll
      for (int nc = 0; nc < 2; nc++) {
        float a = acc[mt][nc][r];
        s1[nc] += a;
        s2[nc] += a * a;
      }
#pragma unroll
  for (int nc = 0; nc < 2; nc++) {
    s1[nc] += __shfl_xor(s1[nc], 16, 64);
    s1[nc] += __shfl_xor(s1[nc], 32, 64);
    s2[nc] += __shfl_xor(s2[nc], 16, 64);
    s2[nc] += __shfl_xor(s2[nc], 32, 64);
  }
  float mu[2], inv[2];
#pragma unroll
  for (int nc = 0; nc < 2; nc++) {
    mu[nc] = s1[nc] * (1.0f / KK);
    float var = s2[nc] * (1.0f / KK) - mu[nc] * mu[nc];
    inv[nc] = rsqrtf(var + 1e-5f);
  }
#pragma unroll
  for (int mt = 0; mt < 10; mt++)
#pragma unroll
    for (int r = 0; r < 4; r++) {
      int k = 16 * mt + 4 * q + r;
      if (k < KK) {
        float g = gamma[k], be = beta[k];
        size_t row = (size_t)(b * KK + k) * HWN + n0 + 32 * w;
        out[row + m16] = (acc[mt][0][r] - mu[0]) * inv[0] * g + be;
        out[row + 16 + m16] = (acc[mt][1][r] - mu[1]) * inv[1] * g + be;
      }
    }
}

// ---------------------------------------------------------------------------
extern "C" void kernel_launch(void* const* d_in, const int* in_sizes, int n_in,
                              void* d_out, int out_size, void* d_ws, size_t ws_size,
                              hipStream_t stream) {
  const float* x = (const float*)d_in[0];
  const float* cls = (const float*)d_in[1];
  const float* Wc = (const float*)d_in[2];
  const float* Wf = (const float*)d_in[3];
  const float* gam = (const float*)d_in[4];
  const float* bet = (const float*)d_in[5];
  float* out = (float*)d_out;

  char* p = (char*)d_ws;
  auto alloc = [&](size_t bytes) {
    char* r = p;
    p += (bytes + 255) & ~(size_t)255;
    return r;
  };
  unsigned short* xT16 = (unsigned short*)alloc((size_t)BB * HWN * CC * 2);
  unsigned short* x16 = (unsigned short*)alloc((size_t)BB * CC * HWN * 2);
  unsigned short* E16 = (unsigned short*)alloc((size_t)BB * KP * HWN * 2);
  unsigned short* ET16 = (unsigned short*)alloc((size_t)BB * HWN * KP * 2);
  float* Scp = (float*)alloc((size_t)BB * NSEG * KK * CC * 4);
  unsigned short* Sc16 = (unsigned short*)alloc((size_t)BB * KP * CC * 2);
  unsigned short* AC16 = (unsigned short*)alloc((size_t)BB * KP * CC * 2);
  unsigned short* CWf16 = (unsigned short*)alloc((size_t)192 * CC * 2);
  unsigned short* cls16 = (unsigned short*)alloc((size_t)KP * CC * 2);
  unsigned short* Wc16 = (unsigned short*)alloc((size_t)CC * CC * 2);
  unsigned short* Wf16 = (unsigned short*)alloc((size_t)CC * CC * 2);
  unsigned short* MT16 = (unsigned short*)alloc((size_t)BB * KP * KP * 2);
  float* rowsum = (float*)alloc(BB * KK * 4);
  float* vvec = (float*)alloc((size_t)BB * HWN * 4);

  t0_prep<<<dim3((CC * CC + 255) / 256), 256, 0, stream>>>(cls, Wc, Wf, cls16, Wc16,
                                                           Wf16, MT16, AC16);
  t1_transpose<<<dim3(HWN / 64, CC / 32, BB), 256, 0, stream>>>(x, xT16, x16);
  g1_mfma<<<dim3(HWN / 128, BB), 256, 0, stream>>>(xT16, cls16, E16, ET16, vvec);
  g2_rowsum<<<dim3(BB * KK), 256, 0, stream>>>(E16, rowsum);
  g4b_cwf<<<dim3(CC / 128), 256, 0, stream>>>(cls16, Wf16, CWf16);
  g3_mfma<<<dim3(CC / 128, NSEG, BB), 256, 0, stream>>>(x16, E16, Scp);
  g5_reduce<<<dim3(BB * KK), 256, 0, stream>>>(Scp, rowsum, Sc16);
  g4a_ac<<<dim3(CC / 128, BB), 256, 0, stream>>>(Sc16, Wc16, cls, AC16);
  g4c_m<<<dim3(3, BB), 256, 0, stream>>>(AC16, CWf16, MT16);
  g6_mfma<<<dim3(HWN / 128, BB), 256, 0, stream>>>(xT16, ET16, vvec, AC16, MT16,
                                                   gam, bet, out);
}

// Round 6
// 820.581 us; speedup vs baseline: 1.1517x; 1.1054x over previous
//
#include <hip/hip_runtime.h>
#include <math.h>

#define BB 8
#define CC 512
#define HWN 16384
#define KK 150
#define KP 160
#define NSEG 16
#define SEGN (HWN / NSEG)  // 1024

typedef short bf8v __attribute__((ext_vector_type(8)));
typedef float f4v __attribute__((ext_vector_type(4)));

static __device__ inline unsigned short f2b(float f) {
  unsigned u = __float_as_uint(f);
  u += 0x7fffu + ((u >> 16) & 1u);
  return (unsigned short)(u >> 16);
}
static __device__ inline float b2f(unsigned short s) {
  return __uint_as_float(((unsigned)s) << 16);
}
static __device__ inline float b2fs(short s) { return b2f((unsigned short)s); }

typedef const __attribute__((address_space(1))) void* gas_p;
typedef __attribute__((address_space(3))) void* las_p;
// async 16B/lane global->LDS (LDS dest = wave base + lane*16, global src per-lane)
static __device__ __forceinline__ void gload16(const void* gp, void* lp) {
  __builtin_amdgcn_global_load_lds((gas_p)gp, (las_p)lp, 16, 0, 0);
}

// ---------------------------------------------------------------------------
// t0: cls16 [160][512] (rows>=150 zero), zero MT16, zero AC16 pad rows,
//     Wc16/Wf16 bf16 conversions.
// ---------------------------------------------------------------------------
__global__ __launch_bounds__(256) void t0_prep(const float* __restrict__ cls,
                                               const float* __restrict__ Wc,
                                               const float* __restrict__ Wf,
                                               unsigned short* __restrict__ cls16,
                                               unsigned short* __restrict__ Wc16,
                                               unsigned short* __restrict__ Wf16,
                                               unsigned short* __restrict__ MT16,
                                               unsigned short* __restrict__ AC16) {
  int i = blockIdx.x * 256 + threadIdx.x;
  if (i < KP * CC) {
    int k = i >> 9, c = i & 511;
    cls16[i] = (k < KK) ? f2b(cls[k * CC + c]) : 0;
  }
  if (i < BB * KP * KP) MT16[i] = 0;
  if (i < BB * (KP - KK) * CC) {
    int b = i / ((KP - KK) * CC);
    int r = i % ((KP - KK) * CC);
    int k = KK + (r >> 9);
    int c = r & 511;
    AC16[((size_t)b * KP + k) * CC + c] = 0;
  }
  if (i < CC * CC) {
    Wc16[i] = f2b(Wc[i]);
    Wf16[i] = f2b(Wf[i]);
  }
}

// ---------------------------------------------------------------------------
// t1: x [b][c][n] fp32 -> xT16 [b][n][c] bf16 (LDS transpose) + x16 [b][c][n]
// ---------------------------------------------------------------------------
__global__ __launch_bounds__(256) void t1_transpose(const float* __restrict__ x,
                                                    unsigned short* __restrict__ xT,
                                                    unsigned short* __restrict__ x16) {
  __shared__ float ts[32][65];
  const int n0 = blockIdx.x * 64, c0 = blockIdx.y * 32, b = blockIdx.z;
  const int tid = threadIdx.x;
  const float* xb = x + (size_t)b * CC * HWN;
  unsigned short* x16o = x16 + (size_t)b * CC * HWN;
#pragma unroll
  for (int i = 0; i < 2; i++) {
    int e = tid + i * 256;  // 0..511
    int c = e >> 4, n4 = (e & 15) * 4;
    float4 v = *(const float4*)&xb[(size_t)(c0 + c) * HWN + n0 + n4];
    ts[c][n4] = v.x;
    ts[c][n4 + 1] = v.y;
    ts[c][n4 + 2] = v.z;
    ts[c][n4 + 3] = v.w;
    ushort4 pk;
    pk.x = f2b(v.x);
    pk.y = f2b(v.y);
    pk.z = f2b(v.z);
    pk.w = f2b(v.w);
    *(ushort4*)&x16o[(size_t)(c0 + c) * HWN + n0 + n4] = pk;
  }
  __syncthreads();
  unsigned short* xo = xT + (size_t)b * HWN * CC;
#pragma unroll
  for (int i = 0; i < 2; i++) {
    int e = tid + i * 256;  // 0..511
    int cg = e & 7, n = e >> 3;
    ushort4 pk;
    pk.x = f2b(ts[4 * cg][n]);
    pk.y = f2b(ts[4 * cg + 1][n]);
    pk.z = f2b(ts[4 * cg + 2][n]);
    pk.w = f2b(ts[4 * cg + 3][n]);
    *(ushort4*)&xo[(size_t)(n0 + n) * CC + c0 + 4 * cg] = pk;
  }
}

// ---------------------------------------------------------------------------
// g1: A[k][n] = sum_c cls[k][c]*x[c][n], m97-style: BOTH operands staged via
// global_load_lds (NO direct global loads in the K-loop -> async queue never
// drained by fragment waits; fragments come from LDS on lgkmcnt).
// A-slice 160x32 (10KB) + B-slice 128x32 (8KB), double-buffered = 36KB LDS.
// Chunk-XOR swizzle on global source + ds_read slot (LDS linear, rule #21).
// Epilogue: E16 + ET16 + vvec (bit-identical to round 2).
// ---------------------------------------------------------------------------
__global__ __launch_bounds__(256) void g1_mfma(const unsigned short* __restrict__ xT,
                                               const unsigned short* __restrict__ cls16,
                                               unsigned short* __restrict__ E16,
                                               unsigned short* __restrict__ ET16,
                                               float* __restrict__ vvec) {
  __shared__ unsigned short sA[2][KP * 32];   // 10 KB each
  __shared__ unsigned short sB[2][128 * 32];  // 8 KB each
  const int n0 = blockIdx.x * 128, b = blockIdx.y;
  const int tid = threadIdx.x, w = tid >> 6, L = tid & 63;
  const int q = L >> 4, m16 = L & 15;
  f4v zf = {0.f, 0.f, 0.f, 0.f};
  f4v acc[10][2];
#pragma unroll
  for (int mt = 0; mt < 10; mt++) { acc[mt][0] = zf; acc[mt][1] = zf; }
  const unsigned short* xbase = xT + (size_t)(b * HWN + n0) * CC;
  const int lr = L >> 2, lch = L & 3;

#define G1_STAGE(buf, c0)                                                      \
  {                                                                            \
    /* B: wave w stages rows [w*32, w*32+32), 2 calls of 16 rows */            \
    _Pragma("unroll") for (int j = 0; j < 2; j++) {                            \
      int row = w * 32 + j * 16 + lr;                                          \
      int ch = lch ^ ((row >> 1) & 3);                                         \
      gload16(xbase + (size_t)row * CC + (c0) + ch * 8,                        \
              &sB[buf][(w * 32 + j * 16) * 32]);                               \
    }                                                                          \
    /* A: 10 calls of 16 rows, waves round-robin (wave-uniform loop) */        \
    for (int i = w; i < 10; i += 4) {                                          \
      int row = 16 * i + lr;                                                   \
      int ch = lch ^ ((row >> 1) & 3);                                         \
      gload16(cls16 + (size_t)row * CC + (c0) + ch * 8, &sA[buf][i * 512]);    \
    }                                                                          \
  }

  G1_STAGE(0, 0);
  __syncthreads();
  const int br0 = w * 32 + m16, br1 = br0 + 16;
  const int bs0 = (q ^ ((br0 >> 1) & 3)) * 8, bs1 = (q ^ ((br1 >> 1) & 3)) * 8;
  for (int s = 0; s < 16; s++) {
    if (s < 15) G1_STAGE((s + 1) & 1, (s + 1) * 32);
    const int cur = s & 1;
    bf8v b0 = *(const bf8v*)&sB[cur][br0 * 32 + bs0];
    bf8v b1 = *(const bf8v*)&sB[cur][br1 * 32 + bs1];
#pragma unroll
    for (int mt = 0; mt < 10; mt++) {
      int ar = 16 * mt + m16;
      bf8v a = *(const bf8v*)&sA[cur][ar * 32 + (q ^ ((ar >> 1) & 3)) * 8];
      acc[mt][0] = __builtin_amdgcn_mfma_f32_16x16x32_bf16(a, b0, acc[mt][0], 0, 0, 0);
      acc[mt][1] = __builtin_amdgcn_mfma_f32_16x16x32_bf16(a, b1, acc[mt][1], 0, 0, 0);
    }
    __syncthreads();
  }
  // ---- epilogue: exp in-register, E16/ET16 stores, vvec ----
  float cs0 = 0.f, cs1 = 0.f;
#pragma unroll
  for (int mt = 0; mt < 10; mt++)
#pragma unroll
    for (int r = 0; r < 4; r++) {
      int k = 16 * mt + 4 * q + r;
      bool valid = k < KK;
      float e0 = valid ? __expf(acc[mt][0][r]) : 0.f;
      float e1 = valid ? __expf(acc[mt][1][r]) : 0.f;
      acc[mt][0][r] = e0;
      acc[mt][1][r] = e1;
      cs0 += e0;
      cs1 += e1;
    }
#pragma unroll
  for (int mt = 0; mt < 10; mt++)
#pragma unroll
    for (int r = 0; r < 4; r++) {
      int k = 16 * mt + 4 * q + r;
      size_t row = ((size_t)(b * KP + k)) * HWN + n0 + 32 * w;
      E16[row + m16] = f2b(acc[mt][0][r]);
      E16[row + 16 + m16] = f2b(acc[mt][1][r]);
    }
  const int nA = n0 + 32 * w + m16;
#pragma unroll
  for (int mt = 0; mt < 10; mt++) {
    unsigned lo0 = (unsigned)f2b(acc[mt][0][0]) | ((unsigned)f2b(acc[mt][0][1]) << 16);
    unsigned hi0 = (unsigned)f2b(acc[mt][0][2]) | ((unsigned)f2b(acc[mt][0][3]) << 16);
    unsigned lo1 = (unsigned)f2b(acc[mt][1][0]) | ((unsigned)f2b(acc[mt][1][1]) << 16);
    unsigned hi1 = (unsigned)f2b(acc[mt][1][2]) | ((unsigned)f2b(acc[mt][1][3]) << 16);
    size_t eoff = ((size_t)(b * HWN + nA)) * KP + 16 * mt + 4 * q;
    *(uint2*)&ET16[eoff] = make_uint2(lo0, hi0);
    *(uint2*)&ET16[eoff + (size_t)16 * KP] = make_uint2(lo1, hi1);
  }
  cs0 += __shfl_xor(cs0, 16, 64);
  cs0 += __shfl_xor(cs0, 32, 64);
  cs1 += __shfl_xor(cs1, 16, 64);
  cs1 += __shfl_xor(cs1, 32, 64);
  if (q == 0) {
    vvec[b * HWN + nA] = 1.0f / cs0;
    vvec[b * HWN + nA + 16] = 1.0f / cs1;
  }
}

// ---------------------------------------------------------------------------
// g2: rowsum[b][k] = sum_n E16[b][k][n]  (coalesced stream, no atomics)
// ---------------------------------------------------------------------------
__global__ __launch_bounds__(256) void g2_rowsum(const unsigned short* __restrict__ E16,
                                                 float* __restrict__ rowsum) {
  const int bk = blockIdx.x;
  const int b = bk / KK, k = bk % KK;
  const bf8v* row = (const bf8v*)(E16 + ((size_t)(b * KP + k)) * HWN);
  __shared__ float red[4];
  const int tid = threadIdx.x, lane = tid & 63, w = tid >> 6;
  float s = 0.f;
  for (int i = tid; i < HWN / 8; i += 256) {
    bf8v u = row[i];
#pragma unroll
    for (int j = 0; j < 8; j++) s += b2fs(u[j]);
  }
#pragma unroll
  for (int o = 32; o > 0; o >>= 1) s += __shfl_down(s, o, 64);
  if (lane == 0) red[w] = s;
  __syncthreads();
  if (tid == 0) rowsum[bk] = red[0] + red[1] + red[2] + red[3];
}

// ---------------------------------------------------------------------------
// g3: Scp[b][seg][k][c] = sum_{n in seg} E[k][n]*x16[c][n]  via MFMA.
// (plain round-2 form — control kernel for the staging experiment)
// ---------------------------------------------------------------------------
__global__ __launch_bounds__(256) void g3_mfma(const unsigned short* __restrict__ x16,
                                               const unsigned short* __restrict__ E16,
                                               float* __restrict__ Scp) {
  const int cblk = blockIdx.x, seg = blockIdx.y, b = blockIdx.z;
  const int tid = threadIdx.x, w = tid >> 6, L = tid & 63;
  const int q = L >> 4, m16 = L & 15;
  f4v zf = {0.f, 0.f, 0.f, 0.f};
  f4v acc[10][2];
#pragma unroll
  for (int mt = 0; mt < 10; mt++) { acc[mt][0] = zf; acc[mt][1] = zf; }
  const unsigned short* eb = E16 + ((size_t)(b * KP + m16)) * HWN + 8 * q;
  const unsigned short* xb = x16 + ((size_t)(b * CC + cblk * 128 + 32 * w + m16)) * HWN + 8 * q;
  const int ns0 = seg * SEGN;
#pragma unroll 2
  for (int nc0 = ns0; nc0 < ns0 + SEGN; nc0 += 32) {
    bf8v x0 = *(const bf8v*)(xb + nc0);
    bf8v x1 = *(const bf8v*)(xb + (size_t)16 * HWN + nc0);
#pragma unroll
    for (int mt = 0; mt < 10; mt++) {
      bf8v a = *(const bf8v*)(eb + (size_t)(16 * mt) * HWN + nc0);
      acc[mt][0] = __builtin_amdgcn_mfma_f32_16x16x32_bf16(a, x0, acc[mt][0], 0, 0, 0);
      acc[mt][1] = __builtin_amdgcn_mfma_f32_16x16x32_bf16(a, x1, acc[mt][1], 0, 0, 0);
    }
  }
#pragma unroll
  for (int mt = 0; mt < 10; mt++)
#pragma unroll
    for (int cc = 0; cc < 2; cc++)
#pragma unroll
      for (int r = 0; r < 4; r++) {
        int k = 16 * mt + 4 * q + r;
        if (k < KK) {
          int c = cblk * 128 + 32 * w + 16 * cc + m16;
          Scp[(((size_t)(b * NSEG + seg)) * KK + k) * CC + c] = acc[mt][cc][r];
        }
      }
}

// ---------------------------------------------------------------------------
// g5: Sc16[b][kp][c] = bf16( (sum_seg Scp)/rowsum )
// ---------------------------------------------------------------------------
__global__ __launch_bounds__(256) void g5_reduce(const float* __restrict__ Scp,
                                                 const float* __restrict__ rowsum,
                                                 unsigned short* __restrict__ Sc16) {
  const int bk = blockIdx.x;
  const int b = bk / KK, k = bk % KK;
  const float inv = 1.0f / rowsum[bk];
  for (int c = threadIdx.x; c < CC; c += 256) {
    float s = 0.f;
    for (int g = 0; g < NSEG; g++)
      s += Scp[(((size_t)(b * NSEG + g)) * KK + k) * CC + c];
    Sc16[((size_t)b * KP + k) * CC + c] = f2b(s * inv);
  }
}

// ---------------------------------------------------------------------------
// g4b: CWf16[k1][j] = bf16( sum_c cls[k1][c]*Wf[j][c] )  via MFMA
// ---------------------------------------------------------------------------
__global__ __launch_bounds__(256) void g4b_cwf(const unsigned short* __restrict__ cls16,
                                               const unsigned short* __restrict__ Wf16,
                                               unsigned short* __restrict__ CWf16) {
  const int tid = threadIdx.x, w = tid >> 6, L = tid & 63;
  const int q = L >> 4, m16 = L & 15;
  const int j0 = blockIdx.x * 128 + 32 * w;
  f4v zf = {0.f, 0.f, 0.f, 0.f};
  f4v acc[10][2];
#pragma unroll
  for (int mt = 0; mt < 10; mt++) { acc[mt][0] = zf; acc[mt][1] = zf; }
  const unsigned short* ar = cls16 + (size_t)m16 * CC + 8 * q;
  const unsigned short* br = Wf16 + (size_t)(j0 + m16) * CC + 8 * q;
#pragma unroll 2
  for (int c0 = 0; c0 < CC; c0 += 32) {
    bf8v b0 = *(const bf8v*)(br + c0);
    bf8v b1 = *(const bf8v*)(br + (size_t)16 * CC + c0);
#pragma unroll
    for (int mt = 0; mt < 10; mt++) {
      bf8v a = *(const bf8v*)(ar + (size_t)(16 * mt) * CC + c0);
      acc[mt][0] = __builtin_amdgcn_mfma_f32_16x16x32_bf16(a, b0, acc[mt][0], 0, 0, 0);
      acc[mt][1] = __builtin_amdgcn_mfma_f32_16x16x32_bf16(a, b1, acc[mt][1], 0, 0, 0);
    }
  }
#pragma unroll
  for (int mt = 0; mt < 10; mt++)
#pragma unroll
    for (int nc = 0; nc < 2; nc++)
#pragma unroll
      for (int r = 0; r < 4; r++) {
        int k1 = 16 * mt + 4 * q + r;  // rows >=150 come out zero (cls16 pad)
        int j = j0 + 16 * nc + m16;
        CWf16[(size_t)k1 * CC + j] = f2b(acc[mt][nc][r]);
      }
}

// ---------------------------------------------------------------------------
// g4a: AC16[b][k][j] = bf16( cls[k][j] + sum_c Sc16[b,k][c]*Wc16[j][c] )
// ---------------------------------------------------------------------------
__global__ __launch_bounds__(256) void g4a_ac(const unsigned short* __restrict__ Sc16,
                                              const unsigned short* __restrict__ Wc16,
                                              const float* __restrict__ cls,
                                              unsigned short* __restrict__ AC16) {
  const int b = blockIdx.y;
  const int tid = threadIdx.x, w = tid >> 6, L = tid & 63;
  const int q = L >> 4, m16 = L & 15;
  const int j0 = blockIdx.x * 128 + 32 * w;
  f4v zf = {0.f, 0.f, 0.f, 0.f};
  f4v acc[10][2];
#pragma unroll
  for (int mt = 0; mt < 10; mt++) { acc[mt][0] = zf; acc[mt][1] = zf; }
  const unsigned short* ar = Sc16 + ((size_t)b * KP + m16) * CC + 8 * q;
  const unsigned short* br = Wc16 + (size_t)(j0 + m16) * CC + 8 * q;
#pragma unroll 2
  for (int c0 = 0; c0 < CC; c0 += 32) {
    bf8v b0 = *(const bf8v*)(br + c0);
    bf8v b1 = *(const bf8v*)(br + (size_t)16 * CC + c0);
#pragma unroll
    for (int mt = 0; mt < 10; mt++) {
      bf8v a = *(const bf8v*)(ar + (size_t)(16 * mt) * CC + c0);
      acc[mt][0] = __builtin_amdgcn_mfma_f32_16x16x32_bf16(a, b0, acc[mt][0], 0, 0, 0);
      acc[mt][1] = __builtin_amdgcn_mfma_f32_16x16x32_bf16(a, b1, acc[mt][1], 0, 0, 0);
    }
  }
#pragma unroll
  for (int mt = 0; mt < 10; mt++)
#pragma unroll
    for (int nc = 0; nc < 2; nc++)
#pragma unroll
      for (int r = 0; r < 4; r++) {
        int k = 16 * mt + 4 * q + r;
        if (k < KK) {
          int j = j0 + 16 * nc + m16;
          AC16[((size_t)b * KP + k) * CC + j] = f2b(cls[k * CC + j] + acc[mt][nc][r]);
        }
      }
}

// ---------------------------------------------------------------------------
// g4c: MT16[b][k2][k1] = bf16( sum_c AC16[b,k2][c]*CWf16[k1][c] )  via MFMA
// ---------------------------------------------------------------------------
__global__ __launch_bounds__(256) void g4c_m(const unsigned short* __restrict__ AC16,
                                             const unsigned short* __restrict__ CWf16,
                                             unsigned short* __restrict__ MT16) {
  const int b = blockIdx.y;
  const int tid = threadIdx.x, w = tid >> 6, L = tid & 63;
  const int q = L >> 4, m16 = L & 15;
  const int k1t = blockIdx.x * 64 + 16 * w;
  f4v zf = {0.f, 0.f, 0.f, 0.f};
  f4v acc[10];
#pragma unroll
  for (int mt = 0; mt < 10; mt++) acc[mt] = zf;
  const unsigned short* ar = AC16 + ((size_t)b * KP + m16) * CC + 8 * q;
  const unsigned short* br = CWf16 + (size_t)(k1t + m16) * CC + 8 * q;
#pragma unroll 2
  for (int c0 = 0; c0 < CC; c0 += 32) {
    bf8v bb = *(const bf8v*)(br + c0);
#pragma unroll
    for (int mt = 0; mt < 10; mt++) {
      bf8v a = *(const bf8v*)(ar + (size_t)(16 * mt) * CC + c0);
      acc[mt] = __builtin_amdgcn_mfma_f32_16x16x32_bf16(a, bb, acc[mt], 0, 0, 0);
    }
  }
  const int k1 = k1t + m16;
#pragma unroll
  for (int mt = 0; mt < 10; mt++)
#pragma unroll
    for (int r = 0; r < 4; r++) {
      int k2 = 16 * mt + 4 * q + r;
      if (k1 < KK) MT16[((size_t)b * KP + k2) * KP + k1] = f2b(acc[mt][r]);
    }
}

// ---------------------------------------------------------------------------
// g6: masks[k][n] = v[n]*(sum_k' MT'[k][k']*ET[n][k']) + sum_c AC[k][c]*xT[n][c]
//     part 2 direct-global (small operands); part 1 fully LDS-staged (A=AC16
//     and B=xT both via global_load_lds, zero direct loads in K-loop).
// ---------------------------------------------------------------------------
__global__ __launch_bounds__(256) void g6_mfma(
    const unsigned short* __restrict__ xT, const unsigned short* __restrict__ ET,
    const float* __restrict__ vvec, const unsigned short* __restrict__ AC16,
    const unsigned short* __restrict__ MT16, const float* __restrict__ gamma,
    const float* __restrict__ beta, float* __restrict__ out) {
  __shared__ unsigned short sA[2][KP * 32];
  __shared__ unsigned short sB[2][128 * 32];
  const int n0 = blockIdx.x * 128, b = blockIdx.y;
  const int tid = threadIdx.x, w = tid >> 6, L = tid & 63;
  const int q = L >> 4, m16 = L & 15;
  f4v zf = {0.f, 0.f, 0.f, 0.f};
  f4v acc[10][2];
#pragma unroll
  for (int mt = 0; mt < 10; mt++) { acc[mt][0] = zf; acc[mt][1] = zf; }

  const unsigned short* xbase = xT + (size_t)(b * HWN + n0) * CC;
  const unsigned short* abase = AC16 + (size_t)b * KP * CC;
  const int lr = L >> 2, lch = L & 3;
#define G6_STAGE(buf, c0)                                                      \
  {                                                                            \
    _Pragma("unroll") for (int j = 0; j < 2; j++) {                            \
      int row = w * 32 + j * 16 + lr;                                          \
      int ch = lch ^ ((row >> 1) & 3);                                         \
      gload16(xbase + (size_t)row * CC + (c0) + ch * 8,                        \
              &sB[buf][(w * 32 + j * 16) * 32]);                               \
    }                                                                          \
    for (int i = w; i < 10; i += 4) {                                          \
      int row = 16 * i + lr;                                                   \
      int ch = lch ^ ((row >> 1) & 3);                                         \
      gload16(abase + (size_t)row * CC + (c0) + ch * 8, &sA[buf][i * 512]);    \
    }                                                                          \
  }
  // issue first-tile staging early; part-2's vmcnt waits just complete it
  G6_STAGE(0, 0);

  // ---- part 2: acc = sum_k' MT'[k][k'] * ET[n][k'] ----
  const unsigned short* et0 = ET + ((size_t)(b * HWN + n0 + 32 * w + m16)) * KP + 8 * q;
  const unsigned short* et1 = et0 + 16 * KP;
  const unsigned short* mb = MT16 + (size_t)b * KP * KP + (size_t)m16 * KP + 8 * q;
#pragma unroll
  for (int kc = 0; kc < KP; kc += 32) {
    bf8v b0 = *(const bf8v*)(et0 + kc);
    bf8v b1 = *(const bf8v*)(et1 + kc);
#pragma unroll
    for (int mt = 0; mt < 10; mt++) {
      bf8v a = *(const bf8v*)(mb + (size_t)(16 * mt) * KP + kc);
      acc[mt][0] = __builtin_amdgcn_mfma_f32_16x16x32_bf16(a, b0, acc[mt][0], 0, 0, 0);
      acc[mt][1] = __builtin_amdgcn_mfma_f32_16x16x32_bf16(a, b1, acc[mt][1], 0, 0, 0);
    }
  }
  const float v0 = vvec[b * HWN + n0 + 32 * w + m16];
  const float v1 = vvec[b * HWN + n0 + 32 * w + 16 + m16];
#pragma unroll
  for (int mt = 0; mt < 10; mt++)
#pragma unroll
    for (int r = 0; r < 4; r++) {
      acc[mt][0][r] *= v0;
      acc[mt][1][r] *= v1;
    }

  // ---- part 1: acc += sum_c AC[k][c]*xT[n][c]  (fully LDS-staged) ----
  __syncthreads();
  const int br0 = w * 32 + m16, br1 = br0 + 16;
  const int bs0 = (q ^ ((br0 >> 1) & 3)) * 8, bs1 = (q ^ ((br1 >> 1) & 3)) * 8;
  for (int s = 0; s < 16; s++) {
    if (s < 15) G6_STAGE((s + 1) & 1, (s + 1) * 32);
    const int cur = s & 1;
    bf8v b0 = *(const bf8v*)&sB[cur][br0 * 32 + bs0];
    bf8v b1 = *(const bf8v*)&sB[cur][br1 * 32 + bs1];
#pragma unroll
    for (int mt = 0; mt < 10; mt++) {
      int ar = 16 * mt + m16;
      bf8v a = *(const bf8v*)&sA[cur][ar * 32 + (q ^ ((ar >> 1) & 3)) * 8];
      acc[mt][0] = __builtin_amdgcn_mfma_f32_16x16x32_bf16(a, b0, acc[mt][0], 0, 0, 0);
      acc[mt][1] = __builtin_amdgcn_mfma_f32_16x16x32_bf16(a, b1, acc[mt][1], 0, 0, 0);
    }
    __syncthreads();
  }

  // ---- LayerNorm over k per n (pad rows are exactly zero) ----
  float s1[2] = {0.f, 0.f}, s2[2] = {0.f, 0.f};
#pragma unroll
  for (int mt = 0; mt < 10; mt++)
#pragma unroll
    for (int r = 0; r < 4; r++)
#pragma unroll
      for (int nc = 0; nc < 2; nc++) {
        float a = acc[mt][nc][r];
        s1[nc] += a;
        s2[nc] += a * a;
      }
#pragma unroll
  for (int nc = 0; nc < 2; nc++) {
    s1[nc] += __shfl_xor(s1[nc], 16, 64);
    s1[nc] += __shfl_xor(s1[nc], 32, 64);
    s2[nc] += __shfl_xor(s2[nc], 16, 64);
    s2[nc] += __shfl_xor(s2[nc], 32, 64);
  }
  float mu[2], inv[2];
#pragma unroll
  for (int nc = 0; nc < 2; nc++) {
    mu[nc] = s1[nc] * (1.0f / KK);
    float var = s2[nc] * (1.0f / KK) - mu[nc] * mu[nc];
    inv[nc] = rsqrtf(var + 1e-5f);
  }
#pragma unroll
  for (int mt = 0; mt < 10; mt++)
#pragma unroll
    for (int r = 0; r < 4; r++) {
      int k = 16 * mt + 4 * q + r;
      if (k < KK) {
        float g = gamma[k], be = beta[k];
        size_t row = (size_t)(b * KK + k) * HWN + n0 + 32 * w;
        out[row + m16] = (acc[mt][0][r] - mu[0]) * inv[0] * g + be;
        out[row + 16 + m16] = (acc[mt][1][r] - mu[1]) * inv[1] * g + be;
      }
    }
}

// ---------------------------------------------------------------------------
extern "C" void kernel_launch(void* const* d_in, const int* in_sizes, int n_in,
                              void* d_out, int out_size, void* d_ws, size_t ws_size,
                              hipStream_t stream) {
  const float* x = (const float*)d_in[0];
  const float* cls = (const float*)d_in[1];
  const float* Wc = (const float*)d_in[2];
  const float* Wf = (const float*)d_in[3];
  const float* gam = (const float*)d_in[4];
  const float* bet = (const float*)d_in[5];
  float* out = (float*)d_out;

  char* p = (char*)d_ws;
  auto alloc = [&](size_t bytes) {
    char* r = p;
    p += (bytes + 255) & ~(size_t)255;
    return r;
  };
  unsigned short* xT16 = (unsigned short*)alloc((size_t)BB * HWN * CC * 2);
  unsigned short* x16 = (unsigned short*)alloc((size_t)BB * CC * HWN * 2);
  unsigned short* E16 = (unsigned short*)alloc((size_t)BB * KP * HWN * 2);
  unsigned short* ET16 = (unsigned short*)alloc((size_t)BB * HWN * KP * 2);
  float* Scp = (float*)alloc((size_t)BB * NSEG * KK * CC * 4);
  unsigned short* Sc16 = (unsigned short*)alloc((size_t)BB * KP * CC * 2);
  unsigned short* AC16 = (unsigned short*)alloc((size_t)BB * KP * CC * 2);
  unsigned short* CWf16 = (unsigned short*)alloc((size_t)192 * CC * 2);
  unsigned short* cls16 = (unsigned short*)alloc((size_t)KP * CC * 2);
  unsigned short* Wc16 = (unsigned short*)alloc((size_t)CC * CC * 2);
  unsigned short* Wf16 = (unsigned short*)alloc((size_t)CC * CC * 2);
  unsigned short* MT16 = (unsigned short*)alloc((size_t)BB * KP * KP * 2);
  float* rowsum = (float*)alloc(BB * KK * 4);
  float* vvec = (float*)alloc((size_t)BB * HWN * 4);

  t0_prep<<<dim3((CC * CC + 255) / 256), 256, 0, stream>>>(cls, Wc, Wf, cls16, Wc16,
                                                           Wf16, MT16, AC16);
  t1_transpose<<<dim3(HWN / 64, CC / 32, BB), 256, 0, stream>>>(x, xT16, x16);
  g1_mfma<<<dim3(HWN / 128, BB), 256, 0, stream>>>(xT16, cls16, E16, ET16, vvec);
  g2_rowsum<<<dim3(BB * KK), 256, 0, stream>>>(E16, rowsum);
  g4b_cwf<<<dim3(CC / 128), 256, 0, stream>>>(cls16, Wf16, CWf16);
  g3_mfma<<<dim3(CC / 128, NSEG, BB), 256, 0, stream>>>(x16, E16, Scp);
  g5_reduce<<<dim3(BB * KK), 256, 0, stream>>>(Scp, rowsum, Sc16);
  g4a_ac<<<dim3(CC / 128, BB), 256, 0, stream>>>(Sc16, Wc16, cls, AC16);
  g4c_m<<<dim3(3, BB), 256, 0, stream>>>(AC16, CWf16, MT16);
  g6_mfma<<<dim3(HWN / 128, BB), 256, 0, stream>>>(xT16, ET16, vvec, AC16, MT16,
                                                   gam, bet, out);
}

// Round 8
// 783.006 us; speedup vs baseline: 1.2070x; 1.0480x over previous
//
#include <hip/hip_runtime.h>
#include <math.h>

#define BB 8
#define CC 512
#define HWN 16384
#define KK 150
#define KP 160
#define NSEG 16
#define SEGN (HWN / NSEG)  // 1024

typedef short bf8v __attribute__((ext_vector_type(8)));
typedef float f4v __attribute__((ext_vector_type(4)));

static __device__ inline unsigned short f2b(float f) {
  unsigned u = __float_as_uint(f);
  u += 0x7fffu + ((u >> 16) & 1u);
  return (unsigned short)(u >> 16);
}
static __device__ inline float b2f(unsigned short s) {
  return __uint_as_float(((unsigned)s) << 16);
}
static __device__ inline float b2fs(short s) { return b2f((unsigned short)s); }

typedef const __attribute__((address_space(1))) void* gas_p;
typedef __attribute__((address_space(3))) void* las_p;
// async 16B/lane global->LDS (LDS dest = wave base + lane*16, global src per-lane)
static __device__ __forceinline__ void gload16(const void* gp, void* lp) {
  __builtin_amdgcn_global_load_lds((gas_p)gp, (las_p)lp, 16, 0, 0);
}

// ---------------------------------------------------------------------------
// t0: cls16 [160][512] (rows>=150 zero), zero MT16, zero AC16 pad rows,
//     Wc16/Wf16 bf16 conversions.
// ---------------------------------------------------------------------------
__global__ __launch_bounds__(256) void t0_prep(const float* __restrict__ cls,
                                               const float* __restrict__ Wc,
                                               const float* __restrict__ Wf,
                                               unsigned short* __restrict__ cls16,
                                               unsigned short* __restrict__ Wc16,
                                               unsigned short* __restrict__ Wf16,
                                               unsigned short* __restrict__ MT16,
                                               unsigned short* __restrict__ AC16) {
  int i = blockIdx.x * 256 + threadIdx.x;
  if (i < KP * CC) {
    int k = i >> 9, c = i & 511;
    cls16[i] = (k < KK) ? f2b(cls[k * CC + c]) : 0;
  }
  if (i < BB * KP * KP) MT16[i] = 0;
  if (i < BB * (KP - KK) * CC) {
    int b = i / ((KP - KK) * CC);
    int r = i % ((KP - KK) * CC);
    int k = KK + (r >> 9);
    int c = r & 511;
    AC16[((size_t)b * KP + k) * CC + c] = 0;
  }
  if (i < CC * CC) {
    Wc16[i] = f2b(Wc[i]);
    Wf16[i] = f2b(Wf[i]);
  }
}

// ---------------------------------------------------------------------------
// t1: x [b][c][n] fp32 -> xT16 [b][n][c] bf16 (LDS transpose) + x16 [b][c][n]
// ---------------------------------------------------------------------------
__global__ __launch_bounds__(256) void t1_transpose(const float* __restrict__ x,
                                                    unsigned short* __restrict__ xT,
                                                    unsigned short* __restrict__ x16) {
  __shared__ float ts[32][65];
  const int n0 = blockIdx.x * 64, c0 = blockIdx.y * 32, b = blockIdx.z;
  const int tid = threadIdx.x;
  const float* xb = x + (size_t)b * CC * HWN;
  unsigned short* x16o = x16 + (size_t)b * CC * HWN;
#pragma unroll
  for (int i = 0; i < 2; i++) {
    int e = tid + i * 256;  // 0..511
    int c = e >> 4, n4 = (e & 15) * 4;
    float4 v = *(const float4*)&xb[(size_t)(c0 + c) * HWN + n0 + n4];
    ts[c][n4] = v.x;
    ts[c][n4 + 1] = v.y;
    ts[c][n4 + 2] = v.z;
    ts[c][n4 + 3] = v.w;
    ushort4 pk;
    pk.x = f2b(v.x);
    pk.y = f2b(v.y);
    pk.z = f2b(v.z);
    pk.w = f2b(v.w);
    *(ushort4*)&x16o[(size_t)(c0 + c) * HWN + n0 + n4] = pk;
  }
  __syncthreads();
  unsigned short* xo = xT + (size_t)b * HWN * CC;
#pragma unroll
  for (int i = 0; i < 2; i++) {
    int e = tid + i * 256;  // 0..511
    int cg = e & 7, n = e >> 3;
    ushort4 pk;
    pk.x = f2b(ts[4 * cg][n]);
    pk.y = f2b(ts[4 * cg + 1][n]);
    pk.z = f2b(ts[4 * cg + 2][n]);
    pk.w = f2b(ts[4 * cg + 3][n]);
    *(ushort4*)&xo[(size_t)(n0 + n) * CC + c0 + 4 * cg] = pk;
  }
}

// ---------------------------------------------------------------------------
// g1: A[k][n] = sum_c cls[k][c]*x[c][n], m97-style: BOTH operands staged via
// global_load_lds (zero direct global loads in the K-loop).
// A-slice 160x32 (10KB) + B-slice 128x32 (8KB), double-buffered = 36KB LDS.
// Epilogue: E16 + ET16 + vvec (bit-identical to round 2).
// ---------------------------------------------------------------------------
__global__ __launch_bounds__(256) void g1_mfma(const unsigned short* __restrict__ xT,
                                               const unsigned short* __restrict__ cls16,
                                               unsigned short* __restrict__ E16,
                                               unsigned short* __restrict__ ET16,
                                               float* __restrict__ vvec) {
  __shared__ unsigned short sA[2][KP * 32];   // 10 KB each
  __shared__ unsigned short sB[2][128 * 32];  // 8 KB each
  const int n0 = blockIdx.x * 128, b = blockIdx.y;
  const int tid = threadIdx.x, w = tid >> 6, L = tid & 63;
  const int q = L >> 4, m16 = L & 15;
  f4v zf = {0.f, 0.f, 0.f, 0.f};
  f4v acc[10][2];
#pragma unroll
  for (int mt = 0; mt < 10; mt++) { acc[mt][0] = zf; acc[mt][1] = zf; }
  const unsigned short* xbase = xT + (size_t)(b * HWN + n0) * CC;
  const int lr = L >> 2, lch = L & 3;

#define G1_STAGE(buf, c0)                                                      \
  {                                                                            \
    _Pragma("unroll") for (int j = 0; j < 2; j++) {                            \
      int row = w * 32 + j * 16 + lr;                                          \
      int ch = lch ^ ((row >> 1) & 3);                                         \
      gload16(xbase + (size_t)row * CC + (c0) + ch * 8,                        \
              &sB[buf][(w * 32 + j * 16) * 32]);                               \
    }                                                                          \
    for (int i = w; i < 10; i += 4) {                                          \
      int row = 16 * i + lr;                                                   \
      int ch = lch ^ ((row >> 1) & 3);                                         \
      gload16(cls16 + (size_t)row * CC + (c0) + ch * 8, &sA[buf][i * 512]);    \
    }                                                                          \
  }

  G1_STAGE(0, 0);
  __syncthreads();
  const int br0 = w * 32 + m16, br1 = br0 + 16;
  const int bs0 = (q ^ ((br0 >> 1) & 3)) * 8, bs1 = (q ^ ((br1 >> 1) & 3)) * 8;
  for (int s = 0; s < 16; s++) {
    if (s < 15) G1_STAGE((s + 1) & 1, (s + 1) * 32);
    const int cur = s & 1;
    bf8v b0 = *(const bf8v*)&sB[cur][br0 * 32 + bs0];
    bf8v b1 = *(const bf8v*)&sB[cur][br1 * 32 + bs1];
#pragma unroll
    for (int mt = 0; mt < 10; mt++) {
      int ar = 16 * mt + m16;
      bf8v a = *(const bf8v*)&sA[cur][ar * 32 + (q ^ ((ar >> 1) & 3)) * 8];
      acc[mt][0] = __builtin_amdgcn_mfma_f32_16x16x32_bf16(a, b0, acc[mt][0], 0, 0, 0);
      acc[mt][1] = __builtin_amdgcn_mfma_f32_16x16x32_bf16(a, b1, acc[mt][1], 0, 0, 0);
    }
    __syncthreads();
  }
  // ---- epilogue: exp in-register, E16/ET16 stores, vvec ----
  float cs0 = 0.f, cs1 = 0.f;
#pragma unroll
  for (int mt = 0; mt < 10; mt++)
#pragma unroll
    for (int r = 0; r < 4; r++) {
      int k = 16 * mt + 4 * q + r;
      bool valid = k < KK;
      float e0 = valid ? __expf(acc[mt][0][r]) : 0.f;
      float e1 = valid ? __expf(acc[mt][1][r]) : 0.f;
      acc[mt][0][r] = e0;
      acc[mt][1][r] = e1;
      cs0 += e0;
      cs1 += e1;
    }
#pragma unroll
  for (int mt = 0; mt < 10; mt++)
#pragma unroll
    for (int r = 0; r < 4; r++) {
      int k = 16 * mt + 4 * q + r;
      size_t row = ((size_t)(b * KP + k)) * HWN + n0 + 32 * w;
      E16[row + m16] = f2b(acc[mt][0][r]);
      E16[row + 16 + m16] = f2b(acc[mt][1][r]);
    }
  const int nA = n0 + 32 * w + m16;
#pragma unroll
  for (int mt = 0; mt < 10; mt++) {
    unsigned lo0 = (unsigned)f2b(acc[mt][0][0]) | ((unsigned)f2b(acc[mt][0][1]) << 16);
    unsigned hi0 = (unsigned)f2b(acc[mt][0][2]) | ((unsigned)f2b(acc[mt][0][3]) << 16);
    unsigned lo1 = (unsigned)f2b(acc[mt][1][0]) | ((unsigned)f2b(acc[mt][1][1]) << 16);
    unsigned hi1 = (unsigned)f2b(acc[mt][1][2]) | ((unsigned)f2b(acc[mt][1][3]) << 16);
    size_t eoff = ((size_t)(b * HWN + nA)) * KP + 16 * mt + 4 * q;
    *(uint2*)&ET16[eoff] = make_uint2(lo0, hi0);
    *(uint2*)&ET16[eoff + (size_t)16 * KP] = make_uint2(lo1, hi1);
  }
  cs0 += __shfl_xor(cs0, 16, 64);
  cs0 += __shfl_xor(cs0, 32, 64);
  cs1 += __shfl_xor(cs1, 16, 64);
  cs1 += __shfl_xor(cs1, 32, 64);
  if (q == 0) {
    vvec[b * HWN + nA] = 1.0f / cs0;
    vvec[b * HWN + nA + 16] = 1.0f / cs1;
  }
}

// ---------------------------------------------------------------------------
// g2: rowsum[b][k] = sum_n E16[b][k][n]  (coalesced stream, no atomics)
// ---------------------------------------------------------------------------
__global__ __launch_bounds__(256) void g2_rowsum(const unsigned short* __restrict__ E16,
                                                 float* __restrict__ rowsum) {
  const int bk = blockIdx.x;
  const int b = bk / KK, k = bk % KK;
  const bf8v* row = (const bf8v*)(E16 + ((size_t)(b * KP + k)) * HWN);
  __shared__ float red[4];
  const int tid = threadIdx.x, lane = tid & 63, w = tid >> 6;
  float s = 0.f;
  for (int i = tid; i < HWN / 8; i += 256) {
    bf8v u = row[i];
#pragma unroll
    for (int j = 0; j < 8; j++) s += b2fs(u[j]);
  }
#pragma unroll
  for (int o = 32; o > 0; o >>= 1) s += __shfl_down(s, o, 64);
  if (lane == 0) red[w] = s;
  __syncthreads();
  if (tid == 0) rowsum[bk] = red[0] + red[1] + red[2] + red[3];
}

// ---------------------------------------------------------------------------
// g3: Scp[b][seg][k][c] = sum_{n in seg} E[k][n]*x16[c][n]  via MFMA,
// m97-style staged like g1 (n plays the K role): A=E16 slice 160 rows,
// B=x16 slice 128 rows, both stride-HWN, 32-n steps, double-buffered LDS.
// ---------------------------------------------------------------------------
__global__ __launch_bounds__(256) void g3_mfma(const unsigned short* __restrict__ x16,
                                               const unsigned short* __restrict__ E16,
                                               float* __restrict__ Scp) {
  __shared__ unsigned short sA[2][KP * 32];   // E rows
  __shared__ unsigned short sB[2][128 * 32];  // x rows
  const int cblk = blockIdx.x, seg = blockIdx.y, b = blockIdx.z;
  const int tid = threadIdx.x, w = tid >> 6, L = tid & 63;
  const int q = L >> 4, m16 = L & 15;
  f4v zf = {0.f, 0.f, 0.f, 0.f};
  f4v acc[10][2];
#pragma unroll
  for (int mt = 0; mt < 10; mt++) { acc[mt][0] = zf; acc[mt][1] = zf; }
  const unsigned short* ebase = E16 + (size_t)(b * KP) * HWN + seg * SEGN;
  const unsigned short* xbase = x16 + (size_t)(b * CC + cblk * 128) * HWN + seg * SEGN;
  const int lr = L >> 2, lch = L & 3;

#define G3_STAGE(buf, nof)                                                     \
  {                                                                            \
    _Pragma("unroll") for (int j = 0; j < 2; j++) {                            \
      int row = w * 32 + j * 16 + lr;                                          \
      int ch = lch ^ ((row >> 1) & 3);                                         \
      gload16(xbase + (size_t)row * HWN + (nof) + ch * 8,                      \
              &sB[buf][(w * 32 + j * 16) * 32]);                               \
    }                                                                          \
    for (int i = w; i < 10; i += 4) {                                          \
      int row = 16 * i + lr;                                                   \
      int ch = lch ^ ((row >> 1) & 3);                                         \
      gload16(ebase + (size_t)row * HWN + (nof) + ch * 8, &sA[buf][i * 512]);  \
    }                                                                          \
  }

  G3_STAGE(0, 0);
  __syncthreads();
  const int br0 = w * 32 + m16, br1 = br0 + 16;  // wave's 32 c-rows
  const int bs0 = (q ^ ((br0 >> 1) & 3)) * 8, bs1 = (q ^ ((br1 >> 1) & 3)) * 8;
  for (int s = 0; s < SEGN / 32; s++) {
    if (s < SEGN / 32 - 1) G3_STAGE((s + 1) & 1, (s + 1) * 32);
    const int cur = s & 1;
    bf8v b0 = *(const bf8v*)&sB[cur][br0 * 32 + bs0];
    bf8v b1 = *(const bf8v*)&sB[cur][br1 * 32 + bs1];
#pragma unroll
    for (int mt = 0; mt < 10; mt++) {
      int ar = 16 * mt + m16;
      bf8v a = *(const bf8v*)&sA[cur][ar * 32 + (q ^ ((ar >> 1) & 3)) * 8];
      acc[mt][0] = __builtin_amdgcn_mfma_f32_16x16x32_bf16(a, b0, acc[mt][0], 0, 0, 0);
      acc[mt][1] = __builtin_amdgcn_mfma_f32_16x16x32_bf16(a, b1, acc[mt][1], 0, 0, 0);
    }
    __syncthreads();
  }
#pragma unroll
  for (int mt = 0; mt < 10; mt++)
#pragma unroll
    for (int cc = 0; cc < 2; cc++)
#pragma unroll
      for (int r = 0; r < 4; r++) {
        int k = 16 * mt + 4 * q + r;
        if (k < KK) {
          int c = cblk * 128 + 32 * w + 16 * cc + m16;
          Scp[(((size_t)(b * NSEG + seg)) * KK + k) * CC + c] = acc[mt][cc][r];
        }
      }
}

// ---------------------------------------------------------------------------
// g5: Sc16[b][kp][c] = bf16( (sum_seg Scp)/rowsum )
// ---------------------------------------------------------------------------
__global__ __launch_bounds__(256) void g5_reduce(const float* __restrict__ Scp,
                                                 const float* __restrict__ rowsum,
                                                 unsigned short* __restrict__ Sc16) {
  const int bk = blockIdx.x;
  const int b = bk / KK, k = bk % KK;
  const float inv = 1.0f / rowsum[bk];
  for (int c = threadIdx.x; c < CC; c += 256) {
    float s = 0.f;
    for (int g = 0; g < NSEG; g++)
      s += Scp[(((size_t)(b * NSEG + g)) * KK + k) * CC + c];
    Sc16[((size_t)b * KP + k) * CC + c] = f2b(s * inv);
  }
}

// ---------------------------------------------------------------------------
// g4b: CWf16[k1][j] = bf16( sum_c cls[k1][c]*Wf[j][c] )  via MFMA
// ---------------------------------------------------------------------------
__global__ __launch_bounds__(256) void g4b_cwf(const unsigned short* __restrict__ cls16,
                                               const unsigned short* __restrict__ Wf16,
                                               unsigned short* __restrict__ CWf16) {
  const int tid = threadIdx.x, w = tid >> 6, L = tid & 63;
  const int q = L >> 4, m16 = L & 15;
  const int j0 = blockIdx.x * 128 + 32 * w;
  f4v zf = {0.f, 0.f, 0.f, 0.f};
  f4v acc[10][2];
#pragma unroll
  for (int mt = 0; mt < 10; mt++) { acc[mt][0] = zf; acc[mt][1] = zf; }
  const unsigned short* ar = cls16 + (size_t)m16 * CC + 8 * q;
  const unsigned short* br = Wf16 + (size_t)(j0 + m16) * CC + 8 * q;
#pragma unroll 2
  for (int c0 = 0; c0 < CC; c0 += 32) {
    bf8v b0 = *(const bf8v*)(br + c0);
    bf8v b1 = *(const bf8v*)(br + (size_t)16 * CC + c0);
#pragma unroll
    for (int mt = 0; mt < 10; mt++) {
      bf8v a = *(const bf8v*)(ar + (size_t)(16 * mt) * CC + c0);
      acc[mt][0] = __builtin_amdgcn_mfma_f32_16x16x32_bf16(a, b0, acc[mt][0], 0, 0, 0);
      acc[mt][1] = __builtin_amdgcn_mfma_f32_16x16x32_bf16(a, b1, acc[mt][1], 0, 0, 0);
    }
  }
#pragma unroll
  for (int mt = 0; mt < 10; mt++)
#pragma unroll
    for (int nc = 0; nc < 2; nc++)
#pragma unroll
      for (int r = 0; r < 4; r++) {
        int k1 = 16 * mt + 4 * q + r;  // rows >=150 come out zero (cls16 pad)
        int j = j0 + 16 * nc + m16;
        CWf16[(size_t)k1 * CC + j] = f2b(acc[mt][nc][r]);
      }
}

// ---------------------------------------------------------------------------
// g4a: AC16[b][k][j] = bf16( cls[k][j] + sum_c Sc16[b,k][c]*Wc16[j][c] )
// ---------------------------------------------------------------------------
__global__ __launch_bounds__(256) void g4a_ac(const unsigned short* __restrict__ Sc16,
                                              const unsigned short* __restrict__ Wc16,
                                              const float* __restrict__ cls,
                                              unsigned short* __restrict__ AC16) {
  const int b = blockIdx.y;
  const int tid = threadIdx.x, w = tid >> 6, L = tid & 63;
  const int q = L >> 4, m16 = L & 15;
  const int j0 = blockIdx.x * 128 + 32 * w;
  f4v zf = {0.f, 0.f, 0.f, 0.f};
  f4v acc[10][2];
#pragma unroll
  for (int mt = 0; mt < 10; mt++) { acc[mt][0] = zf; acc[mt][1] = zf; }
  const unsigned short* ar = Sc16 + ((size_t)b * KP + m16) * CC + 8 * q;
  const unsigned short* br = Wc16 + (size_t)(j0 + m16) * CC + 8 * q;
#pragma unroll 2
  for (int c0 = 0; c0 < CC; c0 += 32) {
    bf8v b0 = *(const bf8v*)(br + c0);
    bf8v b1 = *(const bf8v*)(br + (size_t)16 * CC + c0);
#pragma unroll
    for (int mt = 0; mt < 10; mt++) {
      bf8v a = *(const bf8v*)(ar + (size_t)(16 * mt) * CC + c0);
      acc[mt][0] = __builtin_amdgcn_mfma_f32_16x16x32_bf16(a, b0, acc[mt][0], 0, 0, 0);
      acc[mt][1] = __builtin_amdgcn_mfma_f32_16x16x32_bf16(a, b1, acc[mt][1], 0, 0, 0);
    }
  }
#pragma unroll
  for (int mt = 0; mt < 10; mt++)
#pragma unroll
    for (int nc = 0; nc < 2; nc++)
#pragma unroll
      for (int r = 0; r < 4; r++) {
        int k = 16 * mt + 4 * q + r;
        if (k < KK) {
          int j = j0 + 16 * nc + m16;
          AC16[((size_t)b * KP + k) * CC + j] = f2b(cls[k * CC + j] + acc[mt][nc][r]);
        }
      }
}

// ---------------------------------------------------------------------------
// g4c: MT16[b][k2][k1] = bf16( sum_c AC16[b,k2][c]*CWf16[k1][c] )  via MFMA
// ---------------------------------------------------------------------------
__global__ __launch_bounds__(256) void g4c_m(const unsigned short* __restrict__ AC16,
                                             const unsigned short* __restrict__ CWf16,
                                             unsigned short* __restrict__ MT16) {
  const int b = blockIdx.y;
  const int tid = threadIdx.x, w = tid >> 6, L = tid & 63;
  const int q = L >> 4, m16 = L & 15;
  const int k1t = blockIdx.x * 64 + 16 * w;
  f4v zf = {0.f, 0.f, 0.f, 0.f};
  f4v acc[10];
#pragma unroll
  for (int mt = 0; mt < 10; mt++) acc[mt] = zf;
  const unsigned short* ar = AC16 + ((size_t)b * KP + m16) * CC + 8 * q;
  const unsigned short* br = CWf16 + (size_t)(k1t + m16) * CC + 8 * q;
#pragma unroll 2
  for (int c0 = 0; c0 < CC; c0 += 32) {
    bf8v bb = *(const bf8v*)(br + c0);
#pragma unroll
    for (int mt = 0; mt < 10; mt++) {
      bf8v a = *(const bf8v*)(ar + (size_t)(16 * mt) * CC + c0);
      acc[mt] = __builtin_amdgcn_mfma_f32_16x16x32_bf16(a, bb, acc[mt], 0, 0, 0);
    }
  }
  const int k1 = k1t + m16;
#pragma unroll
  for (int mt = 0; mt < 10; mt++)
#pragma unroll
    for (int r = 0; r < 4; r++) {
      int k2 = 16 * mt + 4 * q + r;
      if (k1 < KK) MT16[((size_t)b * KP + k2) * KP + k1] = f2b(acc[mt][r]);
    }
}

// ---------------------------------------------------------------------------
// g6: masks[k][n] = v[n]*(sum_k' MT'[k][k']*ET[n][k']) + sum_c AC[k][c]*xT[n][c]
//     part 2 direct-global (small operands); part 1 fully LDS-staged.
// ---------------------------------------------------------------------------
__global__ __launch_bounds__(256) void g6_mfma(
    const unsigned short* __restrict__ xT, const unsigned short* __restrict__ ET,
    const float* __restrict__ vvec, const unsigned short* __restrict__ AC16,
    const unsigned short* __restrict__ MT16, const float* __restrict__ gamma,
    const float* __restrict__ beta, float* __restrict__ out) {
  __shared__ unsigned short sA[2][KP * 32];
  __shared__ unsigned short sB[2][128 * 32];
  const int n0 = blockIdx.x * 128, b = blockIdx.y;
  const int tid = threadIdx.x, w = tid >> 6, L = tid & 63;
  const int q = L >> 4, m16 = L & 15;
  f4v zf = {0.f, 0.f, 0.f, 0.f};
  f4v acc[10][2];
#pragma unroll
  for (int mt = 0; mt < 10; mt++) { acc[mt][0] = zf; acc[mt][1] = zf; }

  const unsigned short* xbase = xT + (size_t)(b * HWN + n0) * CC;
  const unsigned short* abase = AC16 + (size_t)b * KP * CC;
  const int lr = L >> 2, lch = L & 3;
#define G6_STAGE(buf, c0)                                                      \
  {                                                                            \
    _Pragma("unroll") for (int j = 0; j < 2; j++) {                            \
      int row = w * 32 + j * 16 + lr;                                          \
      int ch = lch ^ ((row >> 1) & 3);                                         \
      gload16(xbase + (size_t)row * CC + (c0) + ch * 8,                        \
              &sB[buf][(w * 32 + j * 16) * 32]);                               \
    }                                                                          \
    for (int i = w; i < 10; i += 4) {                                          \
      int row = 16 * i + lr;                                                   \
      int ch = lch ^ ((row >> 1) & 3);                                         \
      gload16(abase + (size_t)row * CC + (c0) + ch * 8, &sA[buf][i * 512]);    \
    }                                                                          \
  }
  // issue first-tile staging early; part-2's compute hides its latency
  G6_STAGE(0, 0);

  // ---- part 2: acc = sum_k' MT'[k][k'] * ET[n][k'] ----
  const unsigned short* et0 = ET + ((size_t)(b * HWN + n0 + 32 * w + m16)) * KP + 8 * q;
  const unsigned short* et1 = et0 + 16 * KP;
  const unsigned short* mb = MT16 + (size_t)b * KP * KP + (size_t)m16 * KP + 8 * q;
#pragma unroll
  for (int kc = 0; kc < KP; kc += 32) {
    bf8v b0 = *(const bf8v*)(et0 + kc);
    bf8v b1 = *(const bf8v*)(et1 + kc);
#pragma unroll
    for (int mt = 0; mt < 10; mt++) {
      bf8v a = *(const bf8v*)(mb + (size_t)(16 * mt) * KP + kc);
      acc[mt][0] = __builtin_amdgcn_mfma_f32_16x16x32_bf16(a, b0, acc[mt][0], 0, 0, 0);
      acc[mt][1] = __builtin_amdgcn_mfma_f32_16x16x32_bf16(a, b1, acc[mt][1], 0, 0, 0);
    }
  }
  const float v0 = vvec[b * HWN + n0 + 32 * w + m16];
  const float v1 = vvec[b * HWN + n0 + 32 * w + 16 + m16];
#pragma unroll
  for (int mt = 0; mt < 10; mt++)
#pragma unroll
    for (int r = 0; r < 4; r++) {
      acc[mt][0][r] *= v0;
      acc[mt][1][r] *= v1;
    }

  // ---- part 1: acc += sum_c AC[k][c]*xT[n][c]  (fully LDS-staged) ----
  __syncthreads();
  const int br0 = w * 32 + m16, br1 = br0 + 16;
  const int bs0 = (q ^ ((br0 >> 1) & 3)) * 8, bs1 = (q ^ ((br1 >> 1) & 3)) * 8;
  for (int s = 0; s < 16; s++) {
    if (s < 15) G6_STAGE((s + 1) & 1, (s + 1) * 32);
    const int cur = s & 1;
    bf8v b0 = *(const bf8v*)&sB[cur][br0 * 32 + bs0];
    bf8v b1 = *(const bf8v*)&sB[cur][br1 * 32 + bs1];
#pragma unroll
    for (int mt = 0; mt < 10; mt++) {
      int ar = 16 * mt + m16;
      bf8v a = *(const bf8v*)&sA[cur][ar * 32 + (q ^ ((ar >> 1) & 3)) * 8];
      acc[mt][0] = __builtin_amdgcn_mfma_f32_16x16x32_bf16(a, b0, acc[mt][0], 0, 0, 0);
      acc[mt][1] = __builtin_amdgcn_mfma_f32_16x16x32_bf16(a, b1, acc[mt][1], 0, 0, 0);
    }
    __syncthreads();
  }

  // ---- LayerNorm over k per n (pad rows are exactly zero) ----
  float s1[2] = {0.f, 0.f}, s2[2] = {0.f, 0.f};
#pragma unroll
  for (int mt = 0; mt < 10; mt++)
#pragma unroll
    for (int r = 0; r < 4; r++)
#pragma unroll
      for (int nc = 0; nc < 2; nc++) {
        float a = acc[mt][nc][r];
        s1[nc] += a;
        s2[nc] += a * a;
      }
#pragma unroll
  for (int nc = 0; nc < 2; nc++) {
    s1[nc] += __shfl_xor(s1[nc], 16, 64);
    s1[nc] += __shfl_xor(s1[nc], 32, 64);
    s2[nc] += __shfl_xor(s2[nc], 16, 64);
    s2[nc] += __shfl_xor(s2[nc], 32, 64);
  }
  float mu[2], inv[2];
#pragma unroll
  for (int nc = 0; nc < 2; nc++) {
    mu[nc] = s1[nc] * (1.0f / KK);
    float var = s2[nc] * (1.0f / KK) - mu[nc] * mu[nc];
    inv[nc] = rsqrtf(var + 1e-5f);
  }
#pragma unroll
  for (int mt = 0; mt < 10; mt++)
#pragma unroll
    for (int r = 0; r < 4; r++) {
      int k = 16 * mt + 4 * q + r;
      if (k < KK) {
        float g = gamma[k], be = beta[k];
        size_t row = (size_t)(b * KK + k) * HWN + n0 + 32 * w;
        out[row + m16] = (acc[mt][0][r] - mu[0]) * inv[0] * g + be;
        out[row + 16 + m16] = (acc[mt][1][r] - mu[1]) * inv[1] * g + be;
      }
    }
}

// ---------------------------------------------------------------------------
extern "C" void kernel_launch(void* const* d_in, const int* in_sizes, int n_in,
                              void* d_out, int out_size, void* d_ws, size_t ws_size,
                              hipStream_t stream) {
  const float* x = (const float*)d_in[0];
  const float* cls = (const float*)d_in[1];
  const float* Wc = (const float*)d_in[2];
  const float* Wf = (const float*)d_in[3];
  const float* gam = (const float*)d_in[4];
  const float* bet = (const float*)d_in[5];
  float* out = (float*)d_out;

  char* p = (char*)d_ws;
  auto alloc = [&](size_t bytes) {
    char* r = p;
    p += (bytes + 255) & ~(size_t)255;
    return r;
  };
  unsigned short* xT16 = (unsigned short*)alloc((size_t)BB * HWN * CC * 2);
  unsigned short* x16 = (unsigned short*)alloc((size_t)BB * CC * HWN * 2);
  unsigned short* E16 = (unsigned short*)alloc((size_t)BB * KP * HWN * 2);
  unsigned short* ET16 = (unsigned short*)alloc((size_t)BB * HWN * KP * 2);
  float* Scp = (float*)alloc((size_t)BB * NSEG * KK * CC * 4);
  unsigned short* Sc16 = (unsigned short*)alloc((size_t)BB * KP * CC * 2);
  unsigned short* AC16 = (unsigned short*)alloc((size_t)BB * KP * CC * 2);
  unsigned short* CWf16 = (unsigned short*)alloc((size_t)192 * CC * 2);
  unsigned short* cls16 = (unsigned short*)alloc((size_t)KP * CC * 2);
  unsigned short* Wc16 = (unsigned short*)alloc((size_t)CC * CC * 2);
  unsigned short* Wf16 = (unsigned short*)alloc((size_t)CC * CC * 2);
  unsigned short* MT16 = (unsigned short*)alloc((size_t)BB * KP * KP * 2);
  float* rowsum = (float*)alloc(BB * KK * 4);
  float* vvec = (float*)alloc((size_t)BB * HWN * 4);

  t0_prep<<<dim3((CC * CC + 255) / 256), 256, 0, stream>>>(cls, Wc, Wf, cls16, Wc16,
                                                           Wf16, MT16, AC16);
  t1_transpose<<<dim3(HWN / 64, CC / 32, BB), 256, 0, stream>>>(x, xT16, x16);
  g1_mfma<<<dim3(HWN / 128, BB), 256, 0, stream>>>(xT16, cls16, E16, ET16, vvec);
  g2_rowsum<<<dim3(BB * KK), 256, 0, stream>>>(E16, rowsum);
  g4b_cwf<<<dim3(CC / 128), 256, 0, stream>>>(cls16, Wf16, CWf16);
  g3_mfma<<<dim3(CC / 128, NSEG, BB), 256, 0, stream>>>(x16, E16, Scp);
  g5_reduce<<<dim3(BB * KK), 256, 0, stream>>>(Scp, rowsum, Sc16);
  g4a_ac<<<dim3(CC / 128, BB), 256, 0, stream>>>(Sc16, Wc16, cls, AC16);
  g4c_m<<<dim3(3, BB), 256, 0, stream>>>(AC16, CWf16, MT16);
  g6_mfma<<<dim3(HWN / 128, BB), 256, 0, stream>>>(xT16, ET16, vvec, AC16, MT16,
                                                   gam, bet, out);
}